// Round 8
// baseline (156.640 us; speedup 1.0000x reference)
//
#include <hip/hip_runtime.h>
#include <hip/hip_bf16.h>
#include <cstddef>

#define N_ROWS 8192
#define M_ROWS 8192
#define D_IN   64
#define H_DIM  32
#define T_OUT  8
#define FDIM   48            // 32 features + qv/1 + 1/ck + 14 zero pad

#define NSPLIT   32          // j-splits (blockIdx.y); 2048 blocks = 8/CU
#define JSLICE   (M_ROWS / NSPLIT)   // 256 cols per block
#define JTILE    32
#define NTILES   (JSLICE / JTILE)    // 8 j-tiles per block
#define LOG2E    1.4426950408889634f
#define NHALF_SC (-0.72134752044448169f)   // -0.5*log2(e)

typedef _Float16 half8  __attribute__((ext_vector_type(8)));
typedef _Float16 half4v __attribute__((ext_vector_type(4)));
typedef __fp16   fp16x2 __attribute__((ext_vector_type(2)));
typedef float    f32x16 __attribute__((ext_vector_type(16)));

__device__ __forceinline__ half8 ld_h8(const _Float16* p) {
    return *(const half8*)p;
}

// ---------------------------------------------------------------------------
// Kernel 1: features, column-split (R6 structure, 48-wide output).
// Rows 0..N-1 = MLP(X) scaled by log2e; rows N.. = MLP(Y) unscaled.
// dim32 = X? qv : 1 ; dim33 = X? 1 : ck ; dims 34-47 = 0.
// ---------------------------------------------------------------------------
__global__ __launch_bounds__(256) void feat_kernel(
    const float* __restrict__ X, const float* __restrict__ Y,
    const float* __restrict__ W1, const float* __restrict__ b1,
    const float* __restrict__ W2, const float* __restrict__ b2,
    const float* __restrict__ W3, const float* __restrict__ b3,
    _Float16* __restrict__ fh, _Float16* __restrict__ fl)
{
    __shared__ float xs [32 * 65];
    __shared__ float w1l[64 * 36];
    __shared__ float w2l[32 * 36];
    __shared__ float w3l[32 * 36];
    __shared__ float h1t[32 * 33];
    __shared__ float h2t[32 * 33];
    __shared__ float psums[8 * 32];
    __shared__ float bl[96];

    const int tid = threadIdx.x;
    const int rowbase = blockIdx.x * 32;           // 512 blocks
    const bool isX = rowbase < N_ROWS;
    const float* src = isX ? (X + (size_t)rowbase * D_IN)
                           : (Y + (size_t)(rowbase - N_ROWS) * D_IN);

    {
        const float4* g4 = (const float4*)src;
        int i0 = tid * 2;
        float4 v0 = g4[i0], v1 = g4[i0 + 1];
        int f0 = tid * 8;
        int r = f0 >> 6, c = f0 & 63;
        float* dst = xs + r * 65 + c;
        dst[0] = v0.x; dst[1] = v0.y; dst[2] = v0.z; dst[3] = v0.w;
        dst[4] = v1.x; dst[5] = v1.y; dst[6] = v1.z; dst[7] = v1.w;
    }
    {
        const float4* g4 = (const float4*)W1;
        int i0 = tid * 2;
        float4 v0 = g4[i0], v1 = g4[i0 + 1];
        int f0 = tid * 8;
        int r = f0 >> 5, c = f0 & 31;
        float* dst = w1l + r * 36 + c;
        ((float4*)dst)[0] = v0; ((float4*)dst)[1] = v1;
    }
    {
        int f0 = tid * 4;
        int r = f0 >> 5, c = f0 & 31;
        *(float4*)(w2l + r * 36 + c) = ((const float4*)W2)[tid];
        *(float4*)(w3l + r * 36 + c) = ((const float4*)W3)[tid];
    }
    if (tid < 32) { bl[tid] = b1[tid]; bl[32 + tid] = b2[tid]; bl[64 + tid] = b3[tid]; }
    __syncthreads();

    const int r  = tid & 31;
    const int c0 = (tid >> 5) * 4;

    float4 a1 = *(const float4*)(bl + c0);
    #pragma unroll
    for (int k = 0; k < 64; ++k) {
        float xv = xs[r * 65 + k];
        float4 w = *(const float4*)(w1l + k * 36 + c0);
        a1.x = fmaf(xv, w.x, a1.x);
        a1.y = fmaf(xv, w.y, a1.y);
        a1.z = fmaf(xv, w.z, a1.z);
        a1.w = fmaf(xv, w.w, a1.w);
    }
    h1t[(c0 + 0) * 33 + r] = fmaxf(a1.x, 0.f);
    h1t[(c0 + 1) * 33 + r] = fmaxf(a1.y, 0.f);
    h1t[(c0 + 2) * 33 + r] = fmaxf(a1.z, 0.f);
    h1t[(c0 + 3) * 33 + r] = fmaxf(a1.w, 0.f);
    __syncthreads();

    float4 a2 = *(const float4*)(bl + 32 + c0);
    #pragma unroll
    for (int k = 0; k < 32; ++k) {
        float xv = h1t[k * 33 + r];
        float4 w = *(const float4*)(w2l + k * 36 + c0);
        a2.x = fmaf(xv, w.x, a2.x);
        a2.y = fmaf(xv, w.y, a2.y);
        a2.z = fmaf(xv, w.z, a2.z);
        a2.w = fmaf(xv, w.w, a2.w);
    }
    h2t[(c0 + 0) * 33 + r] = fmaxf(a2.x, 0.f);
    h2t[(c0 + 1) * 33 + r] = fmaxf(a2.y, 0.f);
    h2t[(c0 + 2) * 33 + r] = fmaxf(a2.z, 0.f);
    h2t[(c0 + 3) * 33 + r] = fmaxf(a2.w, 0.f);
    __syncthreads();

    float4 a3 = *(const float4*)(bl + 64 + c0);
    #pragma unroll
    for (int k = 0; k < 32; ++k) {
        float xv = h2t[k * 33 + r];
        float4 w = *(const float4*)(w3l + k * 36 + c0);
        a3.x = fmaf(xv, w.x, a3.x);
        a3.y = fmaf(xv, w.y, a3.y);
        a3.z = fmaf(xv, w.z, a3.z);
        a3.w = fmaf(xv, w.w, a3.w);
    }
    float v0 = fmaxf(a3.x, 0.f), v1 = fmaxf(a3.y, 0.f);
    float v2 = fmaxf(a3.z, 0.f), v3 = fmaxf(a3.w, 0.f);

    psums[(tid >> 5) * 32 + r] = v0 * v0 + v1 * v1 + v2 * v2 + v3 * v3;

    const float scale = isX ? LOG2E : 1.0f;
    union { _Float16 h[4]; uint2 u; } hh, ll;
    float sv0 = v0 * scale, sv1 = v1 * scale, sv2 = v2 * scale, sv3 = v3 * scale;
    hh.h[0] = (_Float16)sv0; hh.h[1] = (_Float16)sv1;
    hh.h[2] = (_Float16)sv2; hh.h[3] = (_Float16)sv3;
    ll.h[0] = (_Float16)(sv0 - (float)hh.h[0]);
    ll.h[1] = (_Float16)(sv1 - (float)hh.h[1]);
    ll.h[2] = (_Float16)(sv2 - (float)hh.h[2]);
    ll.h[3] = (_Float16)(sv3 - (float)hh.h[3]);
    const size_t fo = (size_t)(rowbase + r) * FDIM + c0;
    *(uint2*)(fh + fo) = hh.u;
    *(uint2*)(fl + fo) = ll.u;

    __syncthreads();
    if (tid < 32) {
        float nrm = 0.f;
        #pragma unroll
        for (int g = 0; g < 8; ++g) nrm += psums[g * 32 + tid];
        float qn = NHALF_SC * nrm;
        float d32 = isX ? qn : 1.0f;
        float d33 = isX ? 1.0f : qn;
        union { _Float16 h[16]; uint4 q[2]; } eh, el;
        #pragma unroll
        for (int i = 0; i < 16; ++i) { eh.h[i] = (_Float16)0.f; el.h[i] = (_Float16)0.f; }
        _Float16 h32 = (_Float16)d32, h33 = (_Float16)d33;
        eh.h[0] = h32; eh.h[1] = h33;
        el.h[0] = (_Float16)(d32 - (float)h32);
        el.h[1] = (_Float16)(d33 - (float)h33);
        const size_t eo = (size_t)(rowbase + tid) * FDIM + 32;
        *(uint4*)(fh + eo) = eh.q[0]; *(uint4*)(fh + eo + 8) = eh.q[1];
        *(uint4*)(fl + eo) = el.q[0]; *(uint4*)(fl + eo + 8) = el.q[1];
    }
}

// ---------------------------------------------------------------------------
// Kernel 2: Y_target in PV B-fragment order for mfma_32x32x8_f16.
// yf[((jt*4+g)*64 + l)*4 + i'] = Ytt[j = jt*32 + 8g + 4(l>>5) + i'][t=l&31]
// Ytt[j][t] = Yt[j][t] (t<8), 1 (t==8), 0 (t>8). hi/lo planes.
// ---------------------------------------------------------------------------
__global__ __launch_bounds__(256) void ytt_kernel(
    const float* __restrict__ Yt,
    _Float16* __restrict__ yfh, _Float16* __restrict__ yfl)
{
    const int idx = blockIdx.x * 256 + threadIdx.x;   // 0..65535
    const int lane = idx & 63;
    const int jtg  = idx >> 6;
    const int g    = jtg & 3;
    const int jt   = jtg >> 2;
    const int t    = lane & 31;
    const int h    = lane >> 5;
    const int j    = jt * 32 + g * 8 + h * 4;
    union { _Float16 hh[4]; uint2 u; } H, L;
    #pragma unroll
    for (int i = 0; i < 4; ++i) {
        float v = (t < T_OUT) ? Yt[(size_t)(j + i) * T_OUT + t]
                              : (t == 8 ? 1.0f : 0.0f);
        _Float16 hi = (_Float16)v;
        H.hh[i] = hi;
        L.hh[i] = (_Float16)(v - (float)hi);
    }
    *(uint2*)(yfh + (size_t)idx * 4) = H.u;
    *(uint2*)(yfl + (size_t)idx * 4) = L.u;
}

// ---------------------------------------------------------------------------
// Kernel 3: fused pair kernel, register-only P handoff.
// R7 lesson: dependent MFMA chains (9-deep QK, 12-deep PV) at 2 waves/SIMD
// run at ~29 cyc/MFMA latency. Fix = TLP: NSPLIT 32 -> 2048 blocks = 8
// blocks/CU, launch_bounds(256,8) keeps VGPR<=64 so 8 waves/SIMD interleave
// independent chains on the MFMA pipe. Instruction stream unchanged.
// ---------------------------------------------------------------------------
__global__ __launch_bounds__(256, 8) void pair_kernel(
    const _Float16* __restrict__ fh, const _Float16* __restrict__ fl,
    const _Float16* __restrict__ yfh, const _Float16* __restrict__ yfl,
    float* __restrict__ pout, float* __restrict__ psum)
{
    const int tid  = threadIdx.x;
    const int wave = tid >> 6;
    const int lane = tid & 63;
    const int n    = lane & 31;
    const int h    = lane >> 5;

    const int rowbase = blockIdx.x * 128 + wave * 32;   // Q rows
    const int s       = blockIdx.y;
    const int jstart  = s * JSLICE;

    // Q-side B fragments (persist across j-loop)
    const _Float16* qb  = fh + (size_t)(rowbase + n) * FDIM + h * 8;
    const _Float16* qbl = fl + (size_t)(rowbase + n) * FDIM + h * 8;
    half8 qh0 = ld_h8(qb);        half8 qh1 = ld_h8(qb + 16);
    half8 qh2 = ld_h8(qb + 32);
    half8 ql0 = ld_h8(qbl);       half8 ql1 = ld_h8(qbl + 16);
    half8 ql2 = ld_h8(qbl + 32);

    f32x16 o = {};   // O accumulator: col t = lane&31, row i per reg

    for (int jt = 0; jt < NTILES; ++jt) {
        const int jbase = jstart + jt * JTILE;

        // K-side A fragments
        const _Float16* ka  = fh + (size_t)(N_ROWS + jbase + n) * FDIM + h * 8;
        const _Float16* kal = fl + (size_t)(N_ROWS + jbase + n) * FDIM + h * 8;
        half8 kh0 = ld_h8(ka);        half8 kh1 = ld_h8(ka + 16);
        half8 kh2 = ld_h8(ka + 32);
        half8 kl0 = ld_h8(kal);       half8 kl1 = ld_h8(kal + 16);
        half8 kl2 = ld_h8(kal + 32);

        // S^T = K·Q^T with norms folded in dims 32/33 (acc = log2e*(-sq/2))
        f32x16 acc = {};
        acc = __builtin_amdgcn_mfma_f32_32x32x16_f16(kh0, qh0, acc, 0, 0, 0);
        acc = __builtin_amdgcn_mfma_f32_32x32x16_f16(kh1, qh1, acc, 0, 0, 0);
        acc = __builtin_amdgcn_mfma_f32_32x32x16_f16(kh2, qh2, acc, 0, 0, 0);
        acc = __builtin_amdgcn_mfma_f32_32x32x16_f16(kh0, ql0, acc, 0, 0, 0);
        acc = __builtin_amdgcn_mfma_f32_32x32x16_f16(kh1, ql1, acc, 0, 0, 0);
        acc = __builtin_amdgcn_mfma_f32_32x32x16_f16(kh2, ql2, acc, 0, 0, 0);
        acc = __builtin_amdgcn_mfma_f32_32x32x16_f16(kl0, qh0, acc, 0, 0, 0);
        acc = __builtin_amdgcn_mfma_f32_32x32x16_f16(kl1, qh1, acc, 0, 0, 0);
        acc = __builtin_amdgcn_mfma_f32_32x32x16_f16(kl2, qh2, acc, 0, 0, 0);

        // Epilogue: w = 2^min(acc,0); pack hi/lo straight into PV A-frags.
        half4v phi[4], plo[4];
        #pragma unroll
        for (int g = 0; g < 4; ++g) {
            float w0 = __builtin_amdgcn_exp2f(fminf(acc[4*g+0], 0.f));
            float w1 = __builtin_amdgcn_exp2f(fminf(acc[4*g+1], 0.f));
            float w2 = __builtin_amdgcn_exp2f(fminf(acc[4*g+2], 0.f));
            float w3 = __builtin_amdgcn_exp2f(fminf(acc[4*g+3], 0.f));
            fp16x2 p01 = __builtin_amdgcn_cvt_pkrtz(w0, w1);
            fp16x2 p23 = __builtin_amdgcn_cvt_pkrtz(w2, w3);
            fp16x2 l01 = __builtin_amdgcn_cvt_pkrtz(w0 - (float)p01[0],
                                                    w1 - (float)p01[1]);
            fp16x2 l23 = __builtin_amdgcn_cvt_pkrtz(w2 - (float)p23[0],
                                                    w3 - (float)p23[1]);
            union { unsigned int u[2]; half4v v; } ph, pl;
            ph.u[0] = __builtin_bit_cast(unsigned int, p01);
            ph.u[1] = __builtin_bit_cast(unsigned int, p23);
            pl.u[0] = __builtin_bit_cast(unsigned int, l01);
            pl.u[1] = __builtin_bit_cast(unsigned int, l23);
            phi[g] = ph.v; plo[g] = pl.v;
        }

        // PV: O += P·Ytt via 32x32x8, fragment-ordered B from ws.
        const size_t yb = ((size_t)(((size_t)jstart / JTILE + jt) * 4) * 64 + lane) * 4;
        #pragma unroll
        for (int g = 0; g < 4; ++g) {
            half4v bh = *(const half4v*)(yfh + yb + (size_t)g * 256);
            half4v bl = *(const half4v*)(yfl + yb + (size_t)g * 256);
            o = __builtin_amdgcn_mfma_f32_32x32x8f16(phi[g], bh, o, 0, 0, 0);
            o = __builtin_amdgcn_mfma_f32_32x32x8f16(plo[g], bh, o, 0, 0, 0);
            o = __builtin_amdgcn_mfma_f32_32x32x8f16(phi[g], bl, o, 0, 0, 0);
        }
    }

    // Writeout: col t = lane&31; rows i = (r&3)+8*(r>>2)+4h.
    const int t = n;
    if (t <= 8) {
        #pragma unroll
        for (int r = 0; r < 16; ++r) {
            int i = (r & 3) + 8 * (r >> 2) + 4 * h;
            int row = rowbase + i;
            float v = o[r];
            if (t < 8)
                pout[((size_t)s * N_ROWS + row) * T_OUT + t] = v;
            else
                psum[(size_t)s * N_ROWS + row] = v;
        }
    }
}

// ---------------------------------------------------------------------------
// Kernel 4: reduce partials across NSPLIT j-slices and normalize.
// ---------------------------------------------------------------------------
__global__ __launch_bounds__(256) void reduce_kernel(
    const float* __restrict__ pout, const float* __restrict__ psum,
    float* __restrict__ out)
{
    const int id = blockIdx.x * 256 + threadIdx.x;   // 0..65535
    const int i = id >> 3;
    float sv = 0.f, sw = 0.f;
    #pragma unroll
    for (int s = 0; s < NSPLIT; ++s) {
        sv += pout[(size_t)s * N_ROWS * T_OUT + id];
        sw += psum[(size_t)s * N_ROWS + i];
    }
    out[id] = sv / sw;
}

// ---------------------------------------------------------------------------
extern "C" void kernel_launch(void* const* d_in, const int* in_sizes, int n_in,
                              void* d_out, int out_size, void* d_ws, size_t ws_size,
                              hipStream_t stream)
{
    const float* X  = (const float*)d_in[0];
    const float* Y  = (const float*)d_in[1];
    const float* Yt = (const float*)d_in[2];
    const float* W1 = (const float*)d_in[3];
    const float* b1 = (const float*)d_in[4];
    const float* W2 = (const float*)d_in[5];
    const float* b2 = (const float*)d_in[6];
    const float* W3 = (const float*)d_in[7];
    const float* b3 = (const float*)d_in[8];
    float* out = (float*)d_out;

    char* ws = (char*)d_ws;
    const size_t n_feat = (size_t)(N_ROWS + M_ROWS) * FDIM;            // 786432
    _Float16* fh  = (_Float16*)ws;   ws += n_feat * 2;                 // 1.5 MB
    _Float16* fl  = (_Float16*)ws;   ws += n_feat * 2;                 // 1.5 MB
    const size_t n_yf = (size_t)(M_ROWS / JTILE) * 4 * 64 * 4;         // 262144
    _Float16* yfh = (_Float16*)ws;   ws += n_yf * 2;                   // 512 KB
    _Float16* yfl = (_Float16*)ws;   ws += n_yf * 2;                   // 512 KB
    float*    pout = (float*)ws;     ws += (size_t)NSPLIT * N_ROWS * T_OUT * 4; // 8 MB
    float*    psum = (float*)ws;                                       // 1 MB

    feat_kernel<<<(N_ROWS + M_ROWS) / 32, 256, 0, stream>>>(
        X, Y, W1, b1, W2, b2, W3, b3, fh, fl);
    ytt_kernel<<<(M_ROWS / JTILE) * 4 * 64 / 256, 256, 0, stream>>>(Yt, yfh, yfl);

    dim3 grid2(N_ROWS / 128, NSPLIT);
    pair_kernel<<<grid2, 256, 0, stream>>>(fh, fl, yfh, yfl, pout, psum);

    reduce_kernel<<<(N_ROWS * T_OUT) / 256, 256, 0, stream>>>(pout, psum, out);
}

// Round 9
// 125.683 us; speedup vs baseline: 1.2463x; 1.2463x over previous
//
#include <hip/hip_runtime.h>
#include <hip/hip_bf16.h>
#include <cstddef>

#define N_ROWS 8192
#define M_ROWS 8192
#define D_IN   64
#define H_DIM  32
#define T_OUT  8
#define FDIM   48            // 32 features + qv/1 + 1/ck + 14 zero pad

#define NSPLIT   32          // j-splits (blockIdx.y); 2048 blocks = 8/CU
#define JSLICE   (M_ROWS / NSPLIT)   // 256 cols per block
#define JTILE    32
#define NTILES   (JSLICE / JTILE)    // 8 j-tiles per block
#define LOG2E    1.4426950408889634f
#define NHALF_SC (-0.72134752044448169f)   // -0.5*log2(e)

typedef _Float16 half8  __attribute__((ext_vector_type(8)));
typedef _Float16 half4v __attribute__((ext_vector_type(4)));
typedef __fp16   fp16x2 __attribute__((ext_vector_type(2)));
typedef float    f32x16 __attribute__((ext_vector_type(16)));

__device__ __forceinline__ half8 ld_h8(const _Float16* p) {
    return *(const half8*)p;
}

// ---------------------------------------------------------------------------
// Kernel 1: features, column-split (R6 structure, 48-wide output).
// Rows 0..N-1 = MLP(X) scaled by log2e; rows N.. = MLP(Y) unscaled.
// dim32 = X? qv : 1 ; dim33 = X? 1 : ck ; dims 34-47 = 0.
// ---------------------------------------------------------------------------
__global__ __launch_bounds__(256) void feat_kernel(
    const float* __restrict__ X, const float* __restrict__ Y,
    const float* __restrict__ W1, const float* __restrict__ b1,
    const float* __restrict__ W2, const float* __restrict__ b2,
    const float* __restrict__ W3, const float* __restrict__ b3,
    _Float16* __restrict__ fh, _Float16* __restrict__ fl)
{
    __shared__ float xs [32 * 65];
    __shared__ float w1l[64 * 36];
    __shared__ float w2l[32 * 36];
    __shared__ float w3l[32 * 36];
    __shared__ float h1t[32 * 33];
    __shared__ float h2t[32 * 33];
    __shared__ float psums[8 * 32];
    __shared__ float bl[96];

    const int tid = threadIdx.x;
    const int rowbase = blockIdx.x * 32;           // 512 blocks
    const bool isX = rowbase < N_ROWS;
    const float* src = isX ? (X + (size_t)rowbase * D_IN)
                           : (Y + (size_t)(rowbase - N_ROWS) * D_IN);

    {
        const float4* g4 = (const float4*)src;
        int i0 = tid * 2;
        float4 v0 = g4[i0], v1 = g4[i0 + 1];
        int f0 = tid * 8;
        int r = f0 >> 6, c = f0 & 63;
        float* dst = xs + r * 65 + c;
        dst[0] = v0.x; dst[1] = v0.y; dst[2] = v0.z; dst[3] = v0.w;
        dst[4] = v1.x; dst[5] = v1.y; dst[6] = v1.z; dst[7] = v1.w;
    }
    {
        const float4* g4 = (const float4*)W1;
        int i0 = tid * 2;
        float4 v0 = g4[i0], v1 = g4[i0 + 1];
        int f0 = tid * 8;
        int r = f0 >> 5, c = f0 & 31;
        float* dst = w1l + r * 36 + c;
        ((float4*)dst)[0] = v0; ((float4*)dst)[1] = v1;
    }
    {
        int f0 = tid * 4;
        int r = f0 >> 5, c = f0 & 31;
        *(float4*)(w2l + r * 36 + c) = ((const float4*)W2)[tid];
        *(float4*)(w3l + r * 36 + c) = ((const float4*)W3)[tid];
    }
    if (tid < 32) { bl[tid] = b1[tid]; bl[32 + tid] = b2[tid]; bl[64 + tid] = b3[tid]; }
    __syncthreads();

    const int r  = tid & 31;
    const int c0 = (tid >> 5) * 4;

    float4 a1 = *(const float4*)(bl + c0);
    #pragma unroll
    for (int k = 0; k < 64; ++k) {
        float xv = xs[r * 65 + k];
        float4 w = *(const float4*)(w1l + k * 36 + c0);
        a1.x = fmaf(xv, w.x, a1.x);
        a1.y = fmaf(xv, w.y, a1.y);
        a1.z = fmaf(xv, w.z, a1.z);
        a1.w = fmaf(xv, w.w, a1.w);
    }
    h1t[(c0 + 0) * 33 + r] = fmaxf(a1.x, 0.f);
    h1t[(c0 + 1) * 33 + r] = fmaxf(a1.y, 0.f);
    h1t[(c0 + 2) * 33 + r] = fmaxf(a1.z, 0.f);
    h1t[(c0 + 3) * 33 + r] = fmaxf(a1.w, 0.f);
    __syncthreads();

    float4 a2 = *(const float4*)(bl + 32 + c0);
    #pragma unroll
    for (int k = 0; k < 32; ++k) {
        float xv = h1t[k * 33 + r];
        float4 w = *(const float4*)(w2l + k * 36 + c0);
        a2.x = fmaf(xv, w.x, a2.x);
        a2.y = fmaf(xv, w.y, a2.y);
        a2.z = fmaf(xv, w.z, a2.z);
        a2.w = fmaf(xv, w.w, a2.w);
    }
    h2t[(c0 + 0) * 33 + r] = fmaxf(a2.x, 0.f);
    h2t[(c0 + 1) * 33 + r] = fmaxf(a2.y, 0.f);
    h2t[(c0 + 2) * 33 + r] = fmaxf(a2.z, 0.f);
    h2t[(c0 + 3) * 33 + r] = fmaxf(a2.w, 0.f);
    __syncthreads();

    float4 a3 = *(const float4*)(bl + 64 + c0);
    #pragma unroll
    for (int k = 0; k < 32; ++k) {
        float xv = h2t[k * 33 + r];
        float4 w = *(const float4*)(w3l + k * 36 + c0);
        a3.x = fmaf(xv, w.x, a3.x);
        a3.y = fmaf(xv, w.y, a3.y);
        a3.z = fmaf(xv, w.z, a3.z);
        a3.w = fmaf(xv, w.w, a3.w);
    }
    float v0 = fmaxf(a3.x, 0.f), v1 = fmaxf(a3.y, 0.f);
    float v2 = fmaxf(a3.z, 0.f), v3 = fmaxf(a3.w, 0.f);

    psums[(tid >> 5) * 32 + r] = v0 * v0 + v1 * v1 + v2 * v2 + v3 * v3;

    const float scale = isX ? LOG2E : 1.0f;
    union { _Float16 h[4]; uint2 u; } hh, ll;
    float sv0 = v0 * scale, sv1 = v1 * scale, sv2 = v2 * scale, sv3 = v3 * scale;
    hh.h[0] = (_Float16)sv0; hh.h[1] = (_Float16)sv1;
    hh.h[2] = (_Float16)sv2; hh.h[3] = (_Float16)sv3;
    ll.h[0] = (_Float16)(sv0 - (float)hh.h[0]);
    ll.h[1] = (_Float16)(sv1 - (float)hh.h[1]);
    ll.h[2] = (_Float16)(sv2 - (float)hh.h[2]);
    ll.h[3] = (_Float16)(sv3 - (float)hh.h[3]);
    const size_t fo = (size_t)(rowbase + r) * FDIM + c0;
    *(uint2*)(fh + fo) = hh.u;
    *(uint2*)(fl + fo) = ll.u;

    __syncthreads();
    if (tid < 32) {
        float nrm = 0.f;
        #pragma unroll
        for (int g = 0; g < 8; ++g) nrm += psums[g * 32 + tid];
        float qn = NHALF_SC * nrm;
        float d32 = isX ? qn : 1.0f;
        float d33 = isX ? 1.0f : qn;
        union { _Float16 h[16]; uint4 q[2]; } eh, el;
        #pragma unroll
        for (int i = 0; i < 16; ++i) { eh.h[i] = (_Float16)0.f; el.h[i] = (_Float16)0.f; }
        _Float16 h32 = (_Float16)d32, h33 = (_Float16)d33;
        eh.h[0] = h32; eh.h[1] = h33;
        el.h[0] = (_Float16)(d32 - (float)h32);
        el.h[1] = (_Float16)(d33 - (float)h33);
        const size_t eo = (size_t)(rowbase + tid) * FDIM + 32;
        *(uint4*)(fh + eo) = eh.q[0]; *(uint4*)(fh + eo + 8) = eh.q[1];
        *(uint4*)(fl + eo) = el.q[0]; *(uint4*)(fl + eo + 8) = el.q[1];
    }
}

// ---------------------------------------------------------------------------
// Kernel 2: Y_target in PV B-fragment order for mfma_32x32x8_f16.
// yf[((jt*4+g)*64 + l)*4 + i'] = Ytt[j = jt*32 + 8g + 4(l>>5) + i'][t=l&31]
// Ytt[j][t] = Yt[j][t] (t<8), 1 (t==8), 0 (t>8). hi/lo planes.
// ---------------------------------------------------------------------------
__global__ __launch_bounds__(256) void ytt_kernel(
    const float* __restrict__ Yt,
    _Float16* __restrict__ yfh, _Float16* __restrict__ yfl)
{
    const int idx = blockIdx.x * 256 + threadIdx.x;   // 0..65535
    const int lane = idx & 63;
    const int jtg  = idx >> 6;
    const int g    = jtg & 3;
    const int jt   = jtg >> 2;
    const int t    = lane & 31;
    const int h    = lane >> 5;
    const int j    = jt * 32 + g * 8 + h * 4;
    union { _Float16 hh[4]; uint2 u; } H, L;
    #pragma unroll
    for (int i = 0; i < 4; ++i) {
        float v = (t < T_OUT) ? Yt[(size_t)(j + i) * T_OUT + t]
                              : (t == 8 ? 1.0f : 0.0f);
        _Float16 hi = (_Float16)v;
        H.hh[i] = hi;
        L.hh[i] = (_Float16)(v - (float)hi);
    }
    *(uint2*)(yfh + (size_t)idx * 4) = H.u;
    *(uint2*)(yfl + (size_t)idx * 4) = L.u;
}

// ---------------------------------------------------------------------------
// Kernel 3: fused pair kernel, register-only P handoff.
// R8 lesson: launch_bounds(256,8) forced VGPR=32 -> scratch spills
// (WRITE_SIZE 52MB, 2x slower). This kernel needs ~90 live VGPRs.
// R9: keep the 2048-block grid (8 blocks/CU) for TLP, restore (256,4)
// so the allocator has 128 VGPRs and never spills. Occupancy then comes
// from the grid, not from register starvation.
// ---------------------------------------------------------------------------
__global__ __launch_bounds__(256, 4) void pair_kernel(
    const _Float16* __restrict__ fh, const _Float16* __restrict__ fl,
    const _Float16* __restrict__ yfh, const _Float16* __restrict__ yfl,
    float* __restrict__ pout, float* __restrict__ psum)
{
    const int tid  = threadIdx.x;
    const int wave = tid >> 6;
    const int lane = tid & 63;
    const int n    = lane & 31;
    const int h    = lane >> 5;

    const int rowbase = blockIdx.x * 128 + wave * 32;   // Q rows
    const int s       = blockIdx.y;
    const int jstart  = s * JSLICE;

    // Q-side B fragments (persist across j-loop)
    const _Float16* qb  = fh + (size_t)(rowbase + n) * FDIM + h * 8;
    const _Float16* qbl = fl + (size_t)(rowbase + n) * FDIM + h * 8;
    half8 qh0 = ld_h8(qb);        half8 qh1 = ld_h8(qb + 16);
    half8 qh2 = ld_h8(qb + 32);
    half8 ql0 = ld_h8(qbl);       half8 ql1 = ld_h8(qbl + 16);
    half8 ql2 = ld_h8(qbl + 32);

    f32x16 o = {};   // O accumulator: col t = lane&31, row i per reg

    for (int jt = 0; jt < NTILES; ++jt) {
        const int jbase = jstart + jt * JTILE;

        // K-side A fragments
        const _Float16* ka  = fh + (size_t)(N_ROWS + jbase + n) * FDIM + h * 8;
        const _Float16* kal = fl + (size_t)(N_ROWS + jbase + n) * FDIM + h * 8;
        half8 kh0 = ld_h8(ka);        half8 kh1 = ld_h8(ka + 16);
        half8 kh2 = ld_h8(ka + 32);
        half8 kl0 = ld_h8(kal);       half8 kl1 = ld_h8(kal + 16);
        half8 kl2 = ld_h8(kal + 32);

        // S^T = K·Q^T with norms folded in dims 32/33 (acc = log2e*(-sq/2))
        f32x16 acc = {};
        acc = __builtin_amdgcn_mfma_f32_32x32x16_f16(kh0, qh0, acc, 0, 0, 0);
        acc = __builtin_amdgcn_mfma_f32_32x32x16_f16(kh1, qh1, acc, 0, 0, 0);
        acc = __builtin_amdgcn_mfma_f32_32x32x16_f16(kh2, qh2, acc, 0, 0, 0);
        acc = __builtin_amdgcn_mfma_f32_32x32x16_f16(kh0, ql0, acc, 0, 0, 0);
        acc = __builtin_amdgcn_mfma_f32_32x32x16_f16(kh1, ql1, acc, 0, 0, 0);
        acc = __builtin_amdgcn_mfma_f32_32x32x16_f16(kh2, ql2, acc, 0, 0, 0);
        acc = __builtin_amdgcn_mfma_f32_32x32x16_f16(kl0, qh0, acc, 0, 0, 0);
        acc = __builtin_amdgcn_mfma_f32_32x32x16_f16(kl1, qh1, acc, 0, 0, 0);
        acc = __builtin_amdgcn_mfma_f32_32x32x16_f16(kl2, qh2, acc, 0, 0, 0);

        // Epilogue: w = 2^min(acc,0); pack hi/lo straight into PV A-frags.
        half4v phi[4], plo[4];
        #pragma unroll
        for (int g = 0; g < 4; ++g) {
            float w0 = __builtin_amdgcn_exp2f(fminf(acc[4*g+0], 0.f));
            float w1 = __builtin_amdgcn_exp2f(fminf(acc[4*g+1], 0.f));
            float w2 = __builtin_amdgcn_exp2f(fminf(acc[4*g+2], 0.f));
            float w3 = __builtin_amdgcn_exp2f(fminf(acc[4*g+3], 0.f));
            fp16x2 p01 = __builtin_amdgcn_cvt_pkrtz(w0, w1);
            fp16x2 p23 = __builtin_amdgcn_cvt_pkrtz(w2, w3);
            fp16x2 l01 = __builtin_amdgcn_cvt_pkrtz(w0 - (float)p01[0],
                                                    w1 - (float)p01[1]);
            fp16x2 l23 = __builtin_amdgcn_cvt_pkrtz(w2 - (float)p23[0],
                                                    w3 - (float)p23[1]);
            union { unsigned int u[2]; half4v v; } ph, pl;
            ph.u[0] = __builtin_bit_cast(unsigned int, p01);
            ph.u[1] = __builtin_bit_cast(unsigned int, p23);
            pl.u[0] = __builtin_bit_cast(unsigned int, l01);
            pl.u[1] = __builtin_bit_cast(unsigned int, l23);
            phi[g] = ph.v; plo[g] = pl.v;
        }

        // PV: O += P·Ytt via 32x32x8, fragment-ordered B from ws.
        const size_t yb = ((size_t)(((size_t)jstart / JTILE + jt) * 4) * 64 + lane) * 4;
        #pragma unroll
        for (int g = 0; g < 4; ++g) {
            half4v bh = *(const half4v*)(yfh + yb + (size_t)g * 256);
            half4v bl = *(const half4v*)(yfl + yb + (size_t)g * 256);
            o = __builtin_amdgcn_mfma_f32_32x32x8f16(phi[g], bh, o, 0, 0, 0);
            o = __builtin_amdgcn_mfma_f32_32x32x8f16(plo[g], bh, o, 0, 0, 0);
            o = __builtin_amdgcn_mfma_f32_32x32x8f16(phi[g], bl, o, 0, 0, 0);
        }
    }

    // Writeout: col t = lane&31; rows i = (r&3)+8*(r>>2)+4h.
    const int t = n;
    if (t <= 8) {
        #pragma unroll
        for (int r = 0; r < 16; ++r) {
            int i = (r & 3) + 8 * (r >> 2) + 4 * h;
            int row = rowbase + i;
            float v = o[r];
            if (t < 8)
                pout[((size_t)s * N_ROWS + row) * T_OUT + t] = v;
            else
                psum[(size_t)s * N_ROWS + row] = v;
        }
    }
}

// ---------------------------------------------------------------------------
// Kernel 4: reduce partials across NSPLIT j-slices and normalize.
// ---------------------------------------------------------------------------
__global__ __launch_bounds__(256) void reduce_kernel(
    const float* __restrict__ pout, const float* __restrict__ psum,
    float* __restrict__ out)
{
    const int id = blockIdx.x * 256 + threadIdx.x;   // 0..65535
    const int i = id >> 3;
    float sv = 0.f, sw = 0.f;
    #pragma unroll
    for (int s = 0; s < NSPLIT; ++s) {
        sv += pout[(size_t)s * N_ROWS * T_OUT + id];
        sw += psum[(size_t)s * N_ROWS + i];
    }
    out[id] = sv / sw;
}

// ---------------------------------------------------------------------------
extern "C" void kernel_launch(void* const* d_in, const int* in_sizes, int n_in,
                              void* d_out, int out_size, void* d_ws, size_t ws_size,
                              hipStream_t stream)
{
    const float* X  = (const float*)d_in[0];
    const float* Y  = (const float*)d_in[1];
    const float* Yt = (const float*)d_in[2];
    const float* W1 = (const float*)d_in[3];
    const float* b1 = (const float*)d_in[4];
    const float* W2 = (const float*)d_in[5];
    const float* b2 = (const float*)d_in[6];
    const float* W3 = (const float*)d_in[7];
    const float* b3 = (const float*)d_in[8];
    float* out = (float*)d_out;

    char* ws = (char*)d_ws;
    const size_t n_feat = (size_t)(N_ROWS + M_ROWS) * FDIM;            // 786432
    _Float16* fh  = (_Float16*)ws;   ws += n_feat * 2;                 // 1.5 MB
    _Float16* fl  = (_Float16*)ws;   ws += n_feat * 2;                 // 1.5 MB
    const size_t n_yf = (size_t)(M_ROWS / JTILE) * 4 * 64 * 4;         // 262144
    _Float16* yfh = (_Float16*)ws;   ws += n_yf * 2;                   // 512 KB
    _Float16* yfl = (_Float16*)ws;   ws += n_yf * 2;                   // 512 KB
    float*    pout = (float*)ws;     ws += (size_t)NSPLIT * N_ROWS * T_OUT * 4; // 8 MB
    float*    psum = (float*)ws;                                       // 1 MB

    feat_kernel<<<(N_ROWS + M_ROWS) / 32, 256, 0, stream>>>(
        X, Y, W1, b1, W2, b2, W3, b3, fh, fl);
    ytt_kernel<<<(M_ROWS / JTILE) * 4 * 64 / 256, 256, 0, stream>>>(Yt, yfh, yfl);

    dim3 grid2(N_ROWS / 128, NSPLIT);
    pair_kernel<<<grid2, 256, 0, stream>>>(fh, fl, yfh, yfl, pout, psum);

    reduce_kernel<<<(N_ROWS * T_OUT) / 256, 256, 0, stream>>>(pout, psum, out);
}

// Round 10
// 121.202 us; speedup vs baseline: 1.2924x; 1.0370x over previous
//
#include <hip/hip_runtime.h>
#include <hip/hip_bf16.h>
#include <cstddef>

#define N_ROWS 8192
#define M_ROWS 8192
#define D_IN   64
#define H_DIM  32
#define T_OUT  8
#define FDIM   48            // 32 features + qv/1 + 1/ck + 14 zero pad

#define NSPLIT   32          // j-splits (blockIdx.y); 2048 blocks
#define JSLICE   (M_ROWS / NSPLIT)   // 256 cols per block
#define JTILE    32
#define NTILES   (JSLICE / JTILE)    // 8 j-tiles per block
#define LOG2E    1.4426950408889634f
#define NHALF_SC (-0.72134752044448169f)   // -0.5*log2(e)

typedef _Float16 half8  __attribute__((ext_vector_type(8)));
typedef _Float16 half4v __attribute__((ext_vector_type(4)));
typedef __fp16   fp16x2 __attribute__((ext_vector_type(2)));
typedef float    f32x16 __attribute__((ext_vector_type(16)));

__device__ __forceinline__ half8 ld_h8(const _Float16* p) {
    return *(const half8*)p;
}

// ---------------------------------------------------------------------------
// Feature storage is FRAGMENT-ORDER (R10): for 32-row tile T, chunk c (k-dims
// 16c..16c+15), the 64 lanes' 8-half operand slices are contiguous:
//   addr(tile,c,lane) = ((tile*3 + c)*64 + lane)*8 halves, lane = h*32 + n
// holds feat[row = tile*32 + n][k = 16c + 8h .. +8). This serves BOTH the
// MFMA A- and B-operand of 32x32x16 (identical lane mapping), and makes every
// pair-kernel global load lane-contiguous (16 cache lines/request vs ~48 for
// the old 96B-strided row layout — R9's occupancy-invariant stall).
// ---------------------------------------------------------------------------

// ---------------------------------------------------------------------------
// Kernel 1: features, column-split. Rows 0..N-1 = MLP(X) scaled by log2e;
// rows N.. = MLP(Y) unscaled. dim32 = X? qv : 1 ; dim33 = X? 1 : ck ;
// dims 34-47 = 0. Writes fragment-order hi/lo planes.
// ---------------------------------------------------------------------------
__global__ __launch_bounds__(256) void feat_kernel(
    const float* __restrict__ X, const float* __restrict__ Y,
    const float* __restrict__ W1, const float* __restrict__ b1,
    const float* __restrict__ W2, const float* __restrict__ b2,
    const float* __restrict__ W3, const float* __restrict__ b3,
    _Float16* __restrict__ fh, _Float16* __restrict__ fl)
{
    __shared__ float xs [32 * 65];
    __shared__ float w1l[64 * 36];
    __shared__ float w2l[32 * 36];
    __shared__ float w3l[32 * 36];
    __shared__ float h1t[32 * 33];
    __shared__ float h2t[32 * 33];
    __shared__ float psums[8 * 32];
    __shared__ float bl[96];

    const int tid = threadIdx.x;
    const int rowbase = blockIdx.x * 32;           // 512 blocks
    const bool isX = rowbase < N_ROWS;
    const float* src = isX ? (X + (size_t)rowbase * D_IN)
                           : (Y + (size_t)(rowbase - N_ROWS) * D_IN);

    {
        const float4* g4 = (const float4*)src;
        int i0 = tid * 2;
        float4 v0 = g4[i0], v1 = g4[i0 + 1];
        int f0 = tid * 8;
        int r = f0 >> 6, c = f0 & 63;
        float* dst = xs + r * 65 + c;
        dst[0] = v0.x; dst[1] = v0.y; dst[2] = v0.z; dst[3] = v0.w;
        dst[4] = v1.x; dst[5] = v1.y; dst[6] = v1.z; dst[7] = v1.w;
    }
    {
        const float4* g4 = (const float4*)W1;
        int i0 = tid * 2;
        float4 v0 = g4[i0], v1 = g4[i0 + 1];
        int f0 = tid * 8;
        int r = f0 >> 5, c = f0 & 31;
        float* dst = w1l + r * 36 + c;
        ((float4*)dst)[0] = v0; ((float4*)dst)[1] = v1;
    }
    {
        int f0 = tid * 4;
        int r = f0 >> 5, c = f0 & 31;
        *(float4*)(w2l + r * 36 + c) = ((const float4*)W2)[tid];
        *(float4*)(w3l + r * 36 + c) = ((const float4*)W3)[tid];
    }
    if (tid < 32) { bl[tid] = b1[tid]; bl[32 + tid] = b2[tid]; bl[64 + tid] = b3[tid]; }
    __syncthreads();

    const int r  = tid & 31;
    const int c0 = (tid >> 5) * 4;

    float4 a1 = *(const float4*)(bl + c0);
    #pragma unroll
    for (int k = 0; k < 64; ++k) {
        float xv = xs[r * 65 + k];
        float4 w = *(const float4*)(w1l + k * 36 + c0);
        a1.x = fmaf(xv, w.x, a1.x);
        a1.y = fmaf(xv, w.y, a1.y);
        a1.z = fmaf(xv, w.z, a1.z);
        a1.w = fmaf(xv, w.w, a1.w);
    }
    h1t[(c0 + 0) * 33 + r] = fmaxf(a1.x, 0.f);
    h1t[(c0 + 1) * 33 + r] = fmaxf(a1.y, 0.f);
    h1t[(c0 + 2) * 33 + r] = fmaxf(a1.z, 0.f);
    h1t[(c0 + 3) * 33 + r] = fmaxf(a1.w, 0.f);
    __syncthreads();

    float4 a2 = *(const float4*)(bl + 32 + c0);
    #pragma unroll
    for (int k = 0; k < 32; ++k) {
        float xv = h1t[k * 33 + r];
        float4 w = *(const float4*)(w2l + k * 36 + c0);
        a2.x = fmaf(xv, w.x, a2.x);
        a2.y = fmaf(xv, w.y, a2.y);
        a2.z = fmaf(xv, w.z, a2.z);
        a2.w = fmaf(xv, w.w, a2.w);
    }
    h2t[(c0 + 0) * 33 + r] = fmaxf(a2.x, 0.f);
    h2t[(c0 + 1) * 33 + r] = fmaxf(a2.y, 0.f);
    h2t[(c0 + 2) * 33 + r] = fmaxf(a2.z, 0.f);
    h2t[(c0 + 3) * 33 + r] = fmaxf(a2.w, 0.f);
    __syncthreads();

    float4 a3 = *(const float4*)(bl + 64 + c0);
    #pragma unroll
    for (int k = 0; k < 32; ++k) {
        float xv = h2t[k * 33 + r];
        float4 w = *(const float4*)(w3l + k * 36 + c0);
        a3.x = fmaf(xv, w.x, a3.x);
        a3.y = fmaf(xv, w.y, a3.y);
        a3.z = fmaf(xv, w.z, a3.z);
        a3.w = fmaf(xv, w.w, a3.w);
    }
    float v0 = fmaxf(a3.x, 0.f), v1 = fmaxf(a3.y, 0.f);
    float v2 = fmaxf(a3.z, 0.f), v3 = fmaxf(a3.w, 0.f);

    psums[(tid >> 5) * 32 + r] = v0 * v0 + v1 * v1 + v2 * v2 + v3 * v3;

    const float scale = isX ? LOG2E : 1.0f;
    union { _Float16 h[4]; uint2 u; } hh, ll;
    float sv0 = v0 * scale, sv1 = v1 * scale, sv2 = v2 * scale, sv3 = v3 * scale;
    hh.h[0] = (_Float16)sv0; hh.h[1] = (_Float16)sv1;
    hh.h[2] = (_Float16)sv2; hh.h[3] = (_Float16)sv3;
    ll.h[0] = (_Float16)(sv0 - (float)hh.h[0]);
    ll.h[1] = (_Float16)(sv1 - (float)hh.h[1]);
    ll.h[2] = (_Float16)(sv2 - (float)hh.h[2]);
    ll.h[3] = (_Float16)(sv3 - (float)hh.h[3]);
    // fragment-order write: tile = blockIdx.x, chunk = c0>>4, half = (c0>>3)&1
    {
        const int tile = blockIdx.x;
        const int ch = c0 >> 4, hb = (c0 >> 3) & 1, off = c0 & 7;
        const size_t fi = (((size_t)(tile * 3 + ch) * 64) + hb * 32 + r) * 8 + off;
        *(uint2*)(fh + fi) = hh.u;
        *(uint2*)(fl + fi) = ll.u;
    }

    __syncthreads();
    if (tid < 32) {
        float nrm = 0.f;
        #pragma unroll
        for (int g = 0; g < 8; ++g) nrm += psums[g * 32 + tid];
        float qn = NHALF_SC * nrm;
        float d32 = isX ? qn : 1.0f;
        float d33 = isX ? 1.0f : qn;
        union { _Float16 h[8]; uint4 q; } eh, el, ez;
        #pragma unroll
        for (int i = 0; i < 8; ++i) { eh.h[i] = (_Float16)0.f; el.h[i] = (_Float16)0.f; ez.h[i] = (_Float16)0.f; }
        _Float16 h32 = (_Float16)d32, h33 = (_Float16)d33;
        eh.h[0] = h32; eh.h[1] = h33;
        el.h[0] = (_Float16)(d32 - (float)h32);
        el.h[1] = (_Float16)(d33 - (float)h33);
        const int tile = blockIdx.x;
        const size_t f0 = (((size_t)(tile * 3 + 2) * 64) + tid) * 8;        // dims 32-39
        const size_t f1 = (((size_t)(tile * 3 + 2) * 64) + 32 + tid) * 8;   // dims 40-47
        *(uint4*)(fh + f0) = eh.q;  *(uint4*)(fh + f1) = ez.q;
        *(uint4*)(fl + f0) = el.q;  *(uint4*)(fl + f1) = ez.q;
    }
}

// ---------------------------------------------------------------------------
// Kernel 2: Y_target in PV B-fragment order for mfma_32x32x8_f16.
// yf[((jt*4+g)*64 + l)*4 + i'] = Ytt[j = jt*32 + 8g + 4(l>>5) + i'][t=l&31]
// Ytt[j][t] = Yt[j][t] (t<8), 1 (t==8), 0 (t>8). hi/lo planes.
// ---------------------------------------------------------------------------
__global__ __launch_bounds__(256) void ytt_kernel(
    const float* __restrict__ Yt,
    _Float16* __restrict__ yfh, _Float16* __restrict__ yfl)
{
    const int idx = blockIdx.x * 256 + threadIdx.x;   // 0..65535
    const int lane = idx & 63;
    const int jtg  = idx >> 6;
    const int g    = jtg & 3;
    const int jt   = jtg >> 2;
    const int t    = lane & 31;
    const int h    = lane >> 5;
    const int j    = jt * 32 + g * 8 + h * 4;
    union { _Float16 hh[4]; uint2 u; } H, L;
    #pragma unroll
    for (int i = 0; i < 4; ++i) {
        float v = (t < T_OUT) ? Yt[(size_t)(j + i) * T_OUT + t]
                              : (t == 8 ? 1.0f : 0.0f);
        _Float16 hi = (_Float16)v;
        H.hh[i] = hi;
        L.hh[i] = (_Float16)(v - (float)hi);
    }
    *(uint2*)(yfh + (size_t)idx * 4) = H.u;
    *(uint2*)(yfl + (size_t)idx * 4) = L.u;
}

// ---------------------------------------------------------------------------
// Kernel 3: fused pair kernel, register-only P handoff, contiguous loads.
// R9 lesson: time was invariant to occupancy (R7 vs R9) -> shared-pipe limit:
// the 96B-strided operand loads touch ~48 lines/request in the per-CU
// address pipe. R10: fragment-order layout makes every operand load
// lane-contiguous. PV drops the P-lo term (weights = RTZ16(w) consistently
// in numerator+denominator -> error cancels in the ratio): 8 MFMA, and the
// whole P-lo split/pack VALU disappears.
// ---------------------------------------------------------------------------
__global__ __launch_bounds__(256, 4) void pair_kernel(
    const _Float16* __restrict__ fh, const _Float16* __restrict__ fl,
    const _Float16* __restrict__ yfh, const _Float16* __restrict__ yfl,
    float* __restrict__ pout, float* __restrict__ psum)
{
    const int tid  = threadIdx.x;
    const int wave = tid >> 6;
    const int lane = tid & 63;
    const int n    = lane & 31;
    const int h    = lane >> 5;

    const int rowtile = blockIdx.x * 4 + wave;          // Q 32-row tile
    const int rowbase = rowtile * 32;
    const int s       = blockIdx.y;

    // Q-side B fragments: contiguous fragment-order loads, persist in regs.
    const size_t qoff = ((size_t)rowtile * 3) * 512 + (size_t)lane * 8;
    half8 qh0 = ld_h8(fh + qoff);
    half8 qh1 = ld_h8(fh + qoff + 512);
    half8 qh2 = ld_h8(fh + qoff + 1024);
    half8 ql0 = ld_h8(fl + qoff);
    half8 ql1 = ld_h8(fl + qoff + 512);
    half8 ql2 = ld_h8(fl + qoff + 1024);

    f32x16 o = {};   // O accumulator: col t = lane&31, row i per reg

    const int ktile0 = (N_ROWS / 32) + s * NTILES;

    for (int jt = 0; jt < NTILES; ++jt) {
        // K-side A fragments: contiguous
        const size_t koff = ((size_t)(ktile0 + jt) * 3) * 512 + (size_t)lane * 8;
        half8 kh0 = ld_h8(fh + koff);
        half8 kh1 = ld_h8(fh + koff + 512);
        half8 kh2 = ld_h8(fh + koff + 1024);
        half8 kl0 = ld_h8(fl + koff);
        half8 kl1 = ld_h8(fl + koff + 512);
        half8 kl2 = ld_h8(fl + koff + 1024);

        // S^T = K·Q^T with norms folded in dims 32/33 (acc = log2e*(-sq/2))
        f32x16 acc = {};
        acc = __builtin_amdgcn_mfma_f32_32x32x16_f16(kh0, qh0, acc, 0, 0, 0);
        acc = __builtin_amdgcn_mfma_f32_32x32x16_f16(kh1, qh1, acc, 0, 0, 0);
        acc = __builtin_amdgcn_mfma_f32_32x32x16_f16(kh2, qh2, acc, 0, 0, 0);
        acc = __builtin_amdgcn_mfma_f32_32x32x16_f16(kh0, ql0, acc, 0, 0, 0);
        acc = __builtin_amdgcn_mfma_f32_32x32x16_f16(kh1, ql1, acc, 0, 0, 0);
        acc = __builtin_amdgcn_mfma_f32_32x32x16_f16(kh2, ql2, acc, 0, 0, 0);
        acc = __builtin_amdgcn_mfma_f32_32x32x16_f16(kl0, qh0, acc, 0, 0, 0);
        acc = __builtin_amdgcn_mfma_f32_32x32x16_f16(kl1, qh1, acc, 0, 0, 0);
        acc = __builtin_amdgcn_mfma_f32_32x32x16_f16(kl2, qh2, acc, 0, 0, 0);

        // Epilogue: w = 2^min(acc,0); RTZ-pack hi plane only into PV A-frags.
        half4v phi[4];
        #pragma unroll
        for (int g = 0; g < 4; ++g) {
            float w0 = __builtin_amdgcn_exp2f(fminf(acc[4*g+0], 0.f));
            float w1 = __builtin_amdgcn_exp2f(fminf(acc[4*g+1], 0.f));
            float w2 = __builtin_amdgcn_exp2f(fminf(acc[4*g+2], 0.f));
            float w3 = __builtin_amdgcn_exp2f(fminf(acc[4*g+3], 0.f));
            fp16x2 p01 = __builtin_amdgcn_cvt_pkrtz(w0, w1);
            fp16x2 p23 = __builtin_amdgcn_cvt_pkrtz(w2, w3);
            union { unsigned int u[2]; half4v v; } ph;
            ph.u[0] = __builtin_bit_cast(unsigned int, p01);
            ph.u[1] = __builtin_bit_cast(unsigned int, p23);
            phi[g] = ph.v;
        }

        // PV: O += P_hi·(Ytt_hi + Ytt_lo) via 32x32x8, fragment-ordered B.
        const size_t yb = ((size_t)((s * NTILES + jt) * 4) * 64 + lane) * 4;
        #pragma unroll
        for (int g = 0; g < 4; ++g) {
            half4v bh = *(const half4v*)(yfh + yb + (size_t)g * 256);
            half4v bv = *(const half4v*)(yfl + yb + (size_t)g * 256);
            o = __builtin_amdgcn_mfma_f32_32x32x8f16(phi[g], bh, o, 0, 0, 0);
            o = __builtin_amdgcn_mfma_f32_32x32x8f16(phi[g], bv, o, 0, 0, 0);
        }
    }

    // Writeout: col t = lane&31; rows i = (r&3)+8*(r>>2)+4h.
    const int t = n;
    if (t <= 8) {
        #pragma unroll
        for (int r = 0; r < 16; ++r) {
            int i = (r & 3) + 8 * (r >> 2) + 4 * h;
            int row = rowbase + i;
            float v = o[r];
            if (t < 8)
                pout[((size_t)s * N_ROWS + row) * T_OUT + t] = v;
            else
                psum[(size_t)s * N_ROWS + row] = v;
        }
    }
}

// ---------------------------------------------------------------------------
// Kernel 4: reduce partials across NSPLIT j-slices and normalize.
// ---------------------------------------------------------------------------
__global__ __launch_bounds__(256) void reduce_kernel(
    const float* __restrict__ pout, const float* __restrict__ psum,
    float* __restrict__ out)
{
    const int id = blockIdx.x * 256 + threadIdx.x;   // 0..65535
    const int i = id >> 3;
    float sv = 0.f, sw = 0.f;
    #pragma unroll
    for (int s = 0; s < NSPLIT; ++s) {
        sv += pout[(size_t)s * N_ROWS * T_OUT + id];
        sw += psum[(size_t)s * N_ROWS + i];
    }
    out[id] = sv / sw;
}

// ---------------------------------------------------------------------------
extern "C" void kernel_launch(void* const* d_in, const int* in_sizes, int n_in,
                              void* d_out, int out_size, void* d_ws, size_t ws_size,
                              hipStream_t stream)
{
    const float* X  = (const float*)d_in[0];
    const float* Y  = (const float*)d_in[1];
    const float* Yt = (const float*)d_in[2];
    const float* W1 = (const float*)d_in[3];
    const float* b1 = (const float*)d_in[4];
    const float* W2 = (const float*)d_in[5];
    const float* b2 = (const float*)d_in[6];
    const float* W3 = (const float*)d_in[7];
    const float* b3 = (const float*)d_in[8];
    float* out = (float*)d_out;

    char* ws = (char*)d_ws;
    const size_t n_feat = (size_t)((N_ROWS + M_ROWS) / 32) * 3 * 512;  // 786432 halves
    _Float16* fh  = (_Float16*)ws;   ws += n_feat * 2;                 // 1.5 MB
    _Float16* fl  = (_Float16*)ws;   ws += n_feat * 2;                 // 1.5 MB
    const size_t n_yf = (size_t)(M_ROWS / JTILE) * 4 * 64 * 4;         // 262144
    _Float16* yfh = (_Float16*)ws;   ws += n_yf * 2;                   // 512 KB
    _Float16* yfl = (_Float16*)ws;   ws += n_yf * 2;                   // 512 KB
    float*    pout = (float*)ws;     ws += (size_t)NSPLIT * N_ROWS * T_OUT * 4; // 8 MB
    float*    psum = (float*)ws;                                       // 1 MB

    feat_kernel<<<(N_ROWS + M_ROWS) / 32, 256, 0, stream>>>(
        X, Y, W1, b1, W2, b2, W3, b3, fh, fl);
    ytt_kernel<<<(M_ROWS / JTILE) * 4 * 64 / 256, 256, 0, stream>>>(Yt, yfh, yfl);

    dim3 grid2(N_ROWS / 128, NSPLIT);
    pair_kernel<<<grid2, 256, 0, stream>>>(fh, fl, yfh, yfl, pout, psum);

    reduce_kernel<<<(N_ROWS * T_OUT) / 256, 256, 0, stream>>>(pout, psum, out);
}

// Round 11
// 112.576 us; speedup vs baseline: 1.3914x; 1.0766x over previous
//
#include <hip/hip_runtime.h>
#include <hip/hip_bf16.h>
#include <cstddef>

#define N_ROWS 8192
#define M_ROWS 8192
#define D_IN   64
#define H_DIM  32
#define T_OUT  8
#define FDIM   48            // 32 features + qv/1 + 1/ck + 14 zero pad

#define NSPLIT   32          // j-splits (blockIdx.y); 2048 blocks
#define JSLICE   (M_ROWS / NSPLIT)   // 256 cols per block
#define JTILE    32
#define NTILES   (JSLICE / JTILE)    // 8 j-tiles per block
#define LOG2E    1.4426950408889634f
#define NHALF_SC (-0.72134752044448169f)   // -0.5*log2(e)

// LDS staging buffer layout (per j-tile): K hi 3072 B | K lo 3072 B |
// Y hi 2048 B | Y lo 2048 B  = 10240 B; double-buffered = 20480 B.
#define KH_OFF 0
#define KL_OFF 3072
#define YH_OFF 6144
#define YL_OFF 8192
#define BUFSZ  10240

typedef _Float16 half8  __attribute__((ext_vector_type(8)));
typedef _Float16 half4v __attribute__((ext_vector_type(4)));
typedef __fp16   fp16x2 __attribute__((ext_vector_type(2)));
typedef float    f32x16 __attribute__((ext_vector_type(16)));

__device__ __forceinline__ half8 ld_h8(const _Float16* p) {
    return *(const half8*)p;
}

// ---------------------------------------------------------------------------
// Feature storage is FRAGMENT-ORDER: for 32-row tile T, chunk c (k-dims
// 16c..16c+15), lane l = h*32 + n holds feat[row = T*32+n][k = 16c+8h..+8)
// at ((T*3 + c)*64 + l)*8 halves — contiguous lane*16B, which serves the
// 32x32x16 A- and B-operands AND the global_load_lds wave-uniform+lane*16
// constraint.
// ---------------------------------------------------------------------------

// ---------------------------------------------------------------------------
// Kernel 1: features, column-split. Rows 0..N-1 = MLP(X) scaled by log2e;
// rows N.. = MLP(Y) unscaled. dim32 = X? qv : 1 ; dim33 = X? 1 : ck ;
// dims 34-47 = 0. Writes fragment-order hi/lo planes.
// ---------------------------------------------------------------------------
__global__ __launch_bounds__(256) void feat_kernel(
    const float* __restrict__ X, const float* __restrict__ Y,
    const float* __restrict__ W1, const float* __restrict__ b1,
    const float* __restrict__ W2, const float* __restrict__ b2,
    const float* __restrict__ W3, const float* __restrict__ b3,
    _Float16* __restrict__ fh, _Float16* __restrict__ fl)
{
    __shared__ float xs [32 * 65];
    __shared__ float w1l[64 * 36];
    __shared__ float w2l[32 * 36];
    __shared__ float w3l[32 * 36];
    __shared__ float h1t[32 * 33];
    __shared__ float h2t[32 * 33];
    __shared__ float psums[8 * 32];
    __shared__ float bl[96];

    const int tid = threadIdx.x;
    const int rowbase = blockIdx.x * 32;           // 512 blocks
    const bool isX = rowbase < N_ROWS;
    const float* src = isX ? (X + (size_t)rowbase * D_IN)
                           : (Y + (size_t)(rowbase - N_ROWS) * D_IN);

    {
        const float4* g4 = (const float4*)src;
        int i0 = tid * 2;
        float4 v0 = g4[i0], v1 = g4[i0 + 1];
        int f0 = tid * 8;
        int r = f0 >> 6, c = f0 & 63;
        float* dst = xs + r * 65 + c;
        dst[0] = v0.x; dst[1] = v0.y; dst[2] = v0.z; dst[3] = v0.w;
        dst[4] = v1.x; dst[5] = v1.y; dst[6] = v1.z; dst[7] = v1.w;
    }
    {
        const float4* g4 = (const float4*)W1;
        int i0 = tid * 2;
        float4 v0 = g4[i0], v1 = g4[i0 + 1];
        int f0 = tid * 8;
        int r = f0 >> 5, c = f0 & 31;
        float* dst = w1l + r * 36 + c;
        ((float4*)dst)[0] = v0; ((float4*)dst)[1] = v1;
    }
    {
        int f0 = tid * 4;
        int r = f0 >> 5, c = f0 & 31;
        *(float4*)(w2l + r * 36 + c) = ((const float4*)W2)[tid];
        *(float4*)(w3l + r * 36 + c) = ((const float4*)W3)[tid];
    }
    if (tid < 32) { bl[tid] = b1[tid]; bl[32 + tid] = b2[tid]; bl[64 + tid] = b3[tid]; }
    __syncthreads();

    const int r  = tid & 31;
    const int c0 = (tid >> 5) * 4;

    float4 a1 = *(const float4*)(bl + c0);
    #pragma unroll
    for (int k = 0; k < 64; ++k) {
        float xv = xs[r * 65 + k];
        float4 w = *(const float4*)(w1l + k * 36 + c0);
        a1.x = fmaf(xv, w.x, a1.x);
        a1.y = fmaf(xv, w.y, a1.y);
        a1.z = fmaf(xv, w.z, a1.z);
        a1.w = fmaf(xv, w.w, a1.w);
    }
    h1t[(c0 + 0) * 33 + r] = fmaxf(a1.x, 0.f);
    h1t[(c0 + 1) * 33 + r] = fmaxf(a1.y, 0.f);
    h1t[(c0 + 2) * 33 + r] = fmaxf(a1.z, 0.f);
    h1t[(c0 + 3) * 33 + r] = fmaxf(a1.w, 0.f);
    __syncthreads();

    float4 a2 = *(const float4*)(bl + 32 + c0);
    #pragma unroll
    for (int k = 0; k < 32; ++k) {
        float xv = h1t[k * 33 + r];
        float4 w = *(const float4*)(w2l + k * 36 + c0);
        a2.x = fmaf(xv, w.x, a2.x);
        a2.y = fmaf(xv, w.y, a2.y);
        a2.z = fmaf(xv, w.z, a2.z);
        a2.w = fmaf(xv, w.w, a2.w);
    }
    h2t[(c0 + 0) * 33 + r] = fmaxf(a2.x, 0.f);
    h2t[(c0 + 1) * 33 + r] = fmaxf(a2.y, 0.f);
    h2t[(c0 + 2) * 33 + r] = fmaxf(a2.z, 0.f);
    h2t[(c0 + 3) * 33 + r] = fmaxf(a2.w, 0.f);
    __syncthreads();

    float4 a3 = *(const float4*)(bl + 64 + c0);
    #pragma unroll
    for (int k = 0; k < 32; ++k) {
        float xv = h2t[k * 33 + r];
        float4 w = *(const float4*)(w3l + k * 36 + c0);
        a3.x = fmaf(xv, w.x, a3.x);
        a3.y = fmaf(xv, w.y, a3.y);
        a3.z = fmaf(xv, w.z, a3.z);
        a3.w = fmaf(xv, w.w, a3.w);
    }
    float v0 = fmaxf(a3.x, 0.f), v1 = fmaxf(a3.y, 0.f);
    float v2 = fmaxf(a3.z, 0.f), v3 = fmaxf(a3.w, 0.f);

    psums[(tid >> 5) * 32 + r] = v0 * v0 + v1 * v1 + v2 * v2 + v3 * v3;

    const float scale = isX ? LOG2E : 1.0f;
    union { _Float16 h[4]; uint2 u; } hh, ll;
    float sv0 = v0 * scale, sv1 = v1 * scale, sv2 = v2 * scale, sv3 = v3 * scale;
    hh.h[0] = (_Float16)sv0; hh.h[1] = (_Float16)sv1;
    hh.h[2] = (_Float16)sv2; hh.h[3] = (_Float16)sv3;
    ll.h[0] = (_Float16)(sv0 - (float)hh.h[0]);
    ll.h[1] = (_Float16)(sv1 - (float)hh.h[1]);
    ll.h[2] = (_Float16)(sv2 - (float)hh.h[2]);
    ll.h[3] = (_Float16)(sv3 - (float)hh.h[3]);
    {
        const int tile = blockIdx.x;
        const int ch = c0 >> 4, hb = (c0 >> 3) & 1, off = c0 & 7;
        const size_t fi = (((size_t)(tile * 3 + ch) * 64) + hb * 32 + r) * 8 + off;
        *(uint2*)(fh + fi) = hh.u;
        *(uint2*)(fl + fi) = ll.u;
    }

    __syncthreads();
    if (tid < 32) {
        float nrm = 0.f;
        #pragma unroll
        for (int g = 0; g < 8; ++g) nrm += psums[g * 32 + tid];
        float qn = NHALF_SC * nrm;
        float d32 = isX ? qn : 1.0f;
        float d33 = isX ? 1.0f : qn;
        union { _Float16 h[8]; uint4 q; } eh, el, ez;
        #pragma unroll
        for (int i = 0; i < 8; ++i) { eh.h[i] = (_Float16)0.f; el.h[i] = (_Float16)0.f; ez.h[i] = (_Float16)0.f; }
        _Float16 h32 = (_Float16)d32, h33 = (_Float16)d33;
        eh.h[0] = h32; eh.h[1] = h33;
        el.h[0] = (_Float16)(d32 - (float)h32);
        el.h[1] = (_Float16)(d33 - (float)h33);
        const int tile = blockIdx.x;
        const size_t f0 = (((size_t)(tile * 3 + 2) * 64) + tid) * 8;        // dims 32-39
        const size_t f1 = (((size_t)(tile * 3 + 2) * 64) + 32 + tid) * 8;   // dims 40-47
        *(uint4*)(fh + f0) = eh.q;  *(uint4*)(fh + f1) = ez.q;
        *(uint4*)(fl + f0) = el.q;  *(uint4*)(fl + f1) = ez.q;
    }
}

// ---------------------------------------------------------------------------
// Kernel 2: Y_target in PV B-fragment order for mfma_32x32x8_f16.
// yf[((jt*4+g)*64 + l)*4 + i'] = Ytt[j = jt*32 + 8g + 4(l>>5) + i'][t=l&31]
// Ytt[j][t] = Yt[j][t] (t<8), 1 (t==8), 0 (t>8). hi/lo planes.
// ---------------------------------------------------------------------------
__global__ __launch_bounds__(256) void ytt_kernel(
    const float* __restrict__ Yt,
    _Float16* __restrict__ yfh, _Float16* __restrict__ yfl)
{
    const int idx = blockIdx.x * 256 + threadIdx.x;   // 0..65535
    const int lane = idx & 63;
    const int jtg  = idx >> 6;
    const int g    = jtg & 3;
    const int jt   = jtg >> 2;
    const int t    = lane & 31;
    const int h    = lane >> 5;
    const int j    = jt * 32 + g * 8 + h * 4;
    union { _Float16 hh[4]; uint2 u; } H, L;
    #pragma unroll
    for (int i = 0; i < 4; ++i) {
        float v = (t < T_OUT) ? Yt[(size_t)(j + i) * T_OUT + t]
                              : (t == 8 ? 1.0f : 0.0f);
        _Float16 hi = (_Float16)v;
        H.hh[i] = hi;
        L.hh[i] = (_Float16)(v - (float)hi);
    }
    *(uint2*)(yfh + (size_t)idx * 4) = H.u;
    *(uint2*)(yfl + (size_t)idx * 4) = L.u;
}

// ---------------------------------------------------------------------------
// Kernel 3: fused pair kernel, block-shared LDS staging (R11).
// R10 evidence: time invariant to occupancy/instr-count/addressing, all
// pipes <=35% busy -> shared L2 path saturated (~700 MB/launch @ ~16 TB/s;
// L1 can't catch cross-wave K reuse, waves drift). Fix: the 4 waves of a
// block share (Q-range, K-slice); stage each tile's K-frags (6 KB) +
// Y-frags (4 KB) into LDS ONCE per block via 16B global_load_lds
// (fragment-order = lane-contiguous = the wave-uniform+lane*16 pattern),
// double-buffered with one __syncthreads per tile. Global L2 traffic
// drops 700 -> ~213 MB. Math identical to R10.
// ---------------------------------------------------------------------------
__global__ __launch_bounds__(256, 4) void pair_kernel(
    const _Float16* __restrict__ fh, const _Float16* __restrict__ fl,
    const _Float16* __restrict__ yfh, const _Float16* __restrict__ yfl,
    float* __restrict__ pout, float* __restrict__ psum)
{
    __shared__ char smem[2 * BUFSZ];   // 20480 B

    const int tid  = threadIdx.x;
    const int wave = tid >> 6;
    const int lane = tid & 63;
    const int n    = lane & 31;
    const int h    = lane >> 5;

    const int rowtile = blockIdx.x * 4 + wave;          // Q 32-row tile
    const int rowbase = rowtile * 32;
    const int s       = blockIdx.y;
    const int ktile0  = (N_ROWS / 32) + s * NTILES;

    // Q-side B fragments: contiguous fragment-order loads, persist in regs.
    const size_t qoff = (size_t)rowtile * 1536 + (size_t)lane * 8;
    half8 qh0 = ld_h8(fh + qoff);
    half8 qh1 = ld_h8(fh + qoff + 512);
    half8 qh2 = ld_h8(fh + qoff + 1024);
    half8 ql0 = ld_h8(fl + qoff);
    half8 ql1 = ld_h8(fl + qoff + 512);
    half8 ql2 = ld_h8(fl + qoff + 1024);

    // Stage tile jt into buf: 640 16B chunks, 3 rounds, wave-uniform regions
    // (boundaries 192/384/512/640 all multiples of 64).
    auto prefetch = [&](int jt, char* buf) {
        const char* srcKh = (const char*)(fh + (size_t)(ktile0 + jt) * 1536);
        const char* srcKl = (const char*)(fl + (size_t)(ktile0 + jt) * 1536);
        const char* srcYh = (const char*)(yfh + (size_t)(s * NTILES + jt) * 1024);
        const char* srcYl = (const char*)(yfl + (size_t)(s * NTILES + jt) * 1024);
        #pragma unroll
        for (int r = 0; r < 3; ++r) {
            const int c0 = wave * 64 + r * 256;   // wave-uniform
            const int c  = c0 + lane;
            const char* g; char* l;
            if (c0 < 192)      { g = srcKh + (size_t)c * 16;         l = buf + KH_OFF + c * 16; }
            else if (c0 < 384) { g = srcKl + (size_t)(c - 192) * 16; l = buf + KL_OFF + (c - 192) * 16; }
            else if (c0 < 512) { g = srcYh + (size_t)(c - 384) * 16; l = buf + YH_OFF + (c - 384) * 16; }
            else if (c0 < 640) { g = srcYl + (size_t)(c - 512) * 16; l = buf + YL_OFF + (c - 512) * 16; }
            else break;
            __builtin_amdgcn_global_load_lds(
                (const __attribute__((address_space(1))) void*)g,
                (__attribute__((address_space(3))) void*)l, 16, 0, 0);
        }
    };

    f32x16 o = {};   // O accumulator: col t = lane&31, row i per reg

    prefetch(0, smem);
    __syncthreads();

    for (int jt = 0; jt < NTILES; ++jt) {
        char* cur = smem + (jt & 1) * BUFSZ;
        if (jt + 1 < NTILES) prefetch(jt + 1, smem + ((jt + 1) & 1) * BUFSZ);

        // K-side A fragments from LDS
        half8 kh0 = *(const half8*)(cur + KH_OFF + lane * 16);
        half8 kh1 = *(const half8*)(cur + KH_OFF + 1024 + lane * 16);
        half8 kh2 = *(const half8*)(cur + KH_OFF + 2048 + lane * 16);
        half8 kl0 = *(const half8*)(cur + KL_OFF + lane * 16);
        half8 kl1 = *(const half8*)(cur + KL_OFF + 1024 + lane * 16);
        half8 kl2 = *(const half8*)(cur + KL_OFF + 2048 + lane * 16);

        // S^T = K·Q^T with norms folded in dims 32/33 (acc = log2e*(-sq/2))
        f32x16 acc = {};
        acc = __builtin_amdgcn_mfma_f32_32x32x16_f16(kh0, qh0, acc, 0, 0, 0);
        acc = __builtin_amdgcn_mfma_f32_32x32x16_f16(kh1, qh1, acc, 0, 0, 0);
        acc = __builtin_amdgcn_mfma_f32_32x32x16_f16(kh2, qh2, acc, 0, 0, 0);
        acc = __builtin_amdgcn_mfma_f32_32x32x16_f16(kh0, ql0, acc, 0, 0, 0);
        acc = __builtin_amdgcn_mfma_f32_32x32x16_f16(kh1, ql1, acc, 0, 0, 0);
        acc = __builtin_amdgcn_mfma_f32_32x32x16_f16(kh2, ql2, acc, 0, 0, 0);
        acc = __builtin_amdgcn_mfma_f32_32x32x16_f16(kl0, qh0, acc, 0, 0, 0);
        acc = __builtin_amdgcn_mfma_f32_32x32x16_f16(kl1, qh1, acc, 0, 0, 0);
        acc = __builtin_amdgcn_mfma_f32_32x32x16_f16(kl2, qh2, acc, 0, 0, 0);

        // Epilogue: w = 2^min(acc,0); RTZ-pack hi plane only into PV A-frags.
        half4v phi[4];
        #pragma unroll
        for (int g = 0; g < 4; ++g) {
            float w0 = __builtin_amdgcn_exp2f(fminf(acc[4*g+0], 0.f));
            float w1 = __builtin_amdgcn_exp2f(fminf(acc[4*g+1], 0.f));
            float w2 = __builtin_amdgcn_exp2f(fminf(acc[4*g+2], 0.f));
            float w3 = __builtin_amdgcn_exp2f(fminf(acc[4*g+3], 0.f));
            fp16x2 p01 = __builtin_amdgcn_cvt_pkrtz(w0, w1);
            fp16x2 p23 = __builtin_amdgcn_cvt_pkrtz(w2, w3);
            union { unsigned int u[2]; half4v v; } ph;
            ph.u[0] = __builtin_bit_cast(unsigned int, p01);
            ph.u[1] = __builtin_bit_cast(unsigned int, p23);
            phi[g] = ph.v;
        }

        // PV: O += P_hi·(Ytt_hi + Ytt_lo) via 32x32x8, B-frags from LDS.
        #pragma unroll
        for (int g = 0; g < 4; ++g) {
            half4v bh = *(const half4v*)(cur + YH_OFF + (g * 64 + lane) * 8);
            half4v bv = *(const half4v*)(cur + YL_OFF + (g * 64 + lane) * 8);
            o = __builtin_amdgcn_mfma_f32_32x32x8f16(phi[g], bh, o, 0, 0, 0);
            o = __builtin_amdgcn_mfma_f32_32x32x8f16(phi[g], bv, o, 0, 0, 0);
        }

        __syncthreads();   // all waves' prefetch(jt+1) landed; WAR-safe swap
    }

    // Writeout: col t = lane&31; rows i = (r&3)+8*(r>>2)+4h.
    const int t = n;
    if (t <= 8) {
        #pragma unroll
        for (int r = 0; r < 16; ++r) {
            int i = (r & 3) + 8 * (r >> 2) + 4 * h;
            int row = rowbase + i;
            float v = o[r];
            if (t < 8)
                pout[((size_t)s * N_ROWS + row) * T_OUT + t] = v;
            else
                psum[(size_t)s * N_ROWS + row] = v;
        }
    }
}

// ---------------------------------------------------------------------------
// Kernel 4: reduce partials across NSPLIT j-slices and normalize.
// ---------------------------------------------------------------------------
__global__ __launch_bounds__(256) void reduce_kernel(
    const float* __restrict__ pout, const float* __restrict__ psum,
    float* __restrict__ out)
{
    const int id = blockIdx.x * 256 + threadIdx.x;   // 0..65535
    const int i = id >> 3;
    float sv = 0.f, sw = 0.f;
    #pragma unroll
    for (int s = 0; s < NSPLIT; ++s) {
        sv += pout[(size_t)s * N_ROWS * T_OUT + id];
        sw += psum[(size_t)s * N_ROWS + i];
    }
    out[id] = sv / sw;
}

// ---------------------------------------------------------------------------
extern "C" void kernel_launch(void* const* d_in, const int* in_sizes, int n_in,
                              void* d_out, int out_size, void* d_ws, size_t ws_size,
                              hipStream_t stream)
{
    const float* X  = (const float*)d_in[0];
    const float* Y  = (const float*)d_in[1];
    const float* Yt = (const float*)d_in[2];
    const float* W1 = (const float*)d_in[3];
    const float* b1 = (const float*)d_in[4];
    const float* W2 = (const float*)d_in[5];
    const float* b2 = (const float*)d_in[6];
    const float* W3 = (const float*)d_in[7];
    const float* b3 = (const float*)d_in[8];
    float* out = (float*)d_out;

    char* ws = (char*)d_ws;
    const size_t n_feat = (size_t)((N_ROWS + M_ROWS) / 32) * 3 * 512;  // 786432 halves
    _Float16* fh  = (_Float16*)ws;   ws += n_feat * 2;                 // 1.5 MB
    _Float16* fl  = (_Float16*)ws;   ws += n_feat * 2;                 // 1.5 MB
    const size_t n_yf = (size_t)(M_ROWS / JTILE) * 4 * 64 * 4;         // 262144
    _Float16* yfh = (_Float16*)ws;   ws += n_yf * 2;                   // 512 KB
    _Float16* yfl = (_Float16*)ws;   ws += n_yf * 2;                   // 512 KB
    float*    pout = (float*)ws;     ws += (size_t)NSPLIT * N_ROWS * T_OUT * 4; // 8 MB
    float*    psum = (float*)ws;                                       // 1 MB

    feat_kernel<<<(N_ROWS + M_ROWS) / 32, 256, 0, stream>>>(
        X, Y, W1, b1, W2, b2, W3, b3, fh, fl);
    ytt_kernel<<<(M_ROWS / JTILE) * 4 * 64 / 256, 256, 0, stream>>>(Yt, yfh, yfl);

    dim3 grid2(N_ROWS / 128, NSPLIT);
    pair_kernel<<<grid2, 256, 0, stream>>>(fh, fl, yfh, yfl, pout, psum);

    reduce_kernel<<<(N_ROWS * T_OUT) / 256, 256, 0, stream>>>(pout, psum, out);
}

// Round 12
// 111.199 us; speedup vs baseline: 1.4086x; 1.0124x over previous
//
#include <hip/hip_runtime.h>
#include <hip/hip_bf16.h>
#include <cstddef>

#define N_ROWS 8192
#define M_ROWS 8192
#define D_IN   64
#define H_DIM  32
#define T_OUT  8
#define FDIM   48            // 32 features + qv/1 + 1/ck + 14 zero pad

#define NSPLIT   32          // j-splits (blockIdx.y); 2048 blocks
#define JSLICE   (M_ROWS / NSPLIT)   // 256 cols per block
#define JTILE    32
#define NTILES   (JSLICE / JTILE)    // 8 j-tiles per block
#define LOG2E    1.4426950408889634f
#define NHALF_SC (-0.72134752044448169f)   // -0.5*log2(e)

// LDS per j-tile: K hi 3072 | K lo 3072 | Y hi 2048 | Y lo 2048 = 10240 B.
// Stage = 2 tiles = 20480 B; double-buffered = 40960 B (4 blocks/CU).
#define KH_OFF 0
#define KL_OFF 3072
#define YH_OFF 6144
#define YL_OFF 8192
#define BUFSZ  10240
#define STAGESZ (2 * BUFSZ)

typedef _Float16 half8  __attribute__((ext_vector_type(8)));
typedef _Float16 half4v __attribute__((ext_vector_type(4)));
typedef __fp16   fp16x2 __attribute__((ext_vector_type(2)));
typedef float    f32x16 __attribute__((ext_vector_type(16)));

__device__ __forceinline__ half8 ld_h8(const _Float16* p) {
    return *(const half8*)p;
}

// ---------------------------------------------------------------------------
// Feature storage is FRAGMENT-ORDER: for 32-row tile T, chunk c (k-dims
// 16c..16c+15), lane l = h*32 + n holds feat[row = T*32+n][k = 16c+8h..+8)
// at ((T*3 + c)*64 + l)*8 halves — lane-contiguous 16B slices (serves the
// 32x32x16 A/B operands AND global_load_lds's uniform-base+lane*16 rule).
// ---------------------------------------------------------------------------

// ---------------------------------------------------------------------------
// Kernel 1 (fused prep): blocks 0..511 compute features (column-split MLP);
// blocks 512..767 build Y_target PV B-fragments. One launch instead of two.
// ---------------------------------------------------------------------------
__global__ __launch_bounds__(256) void prep_kernel(
    const float* __restrict__ X, const float* __restrict__ Y,
    const float* __restrict__ Yt,
    const float* __restrict__ W1, const float* __restrict__ b1,
    const float* __restrict__ W2, const float* __restrict__ b2,
    const float* __restrict__ W3, const float* __restrict__ b3,
    _Float16* __restrict__ fh, _Float16* __restrict__ fl,
    _Float16* __restrict__ yfh, _Float16* __restrict__ yfl)
{
    __shared__ float xs [32 * 65];
    __shared__ float w1l[64 * 36];
    __shared__ float w2l[32 * 36];
    __shared__ float w3l[32 * 36];
    __shared__ float h1t[32 * 33];
    __shared__ float h2t[32 * 33];
    __shared__ float psums[8 * 32];
    __shared__ float bl[96];

    const int tid = threadIdx.x;

    if (blockIdx.x >= 512) {
        // ---- ytt part: Y_target in PV B-fragment order for 32x32x8 ----
        // yf[((jt*4+g)*64+l)*4+i'] = Ytt[j = jt*32+8g+4(l>>5)+i'][t=l&31]
        const int idx = (blockIdx.x - 512) * 256 + tid;   // 0..65535
        const int lane = idx & 63;
        const int jtg  = idx >> 6;
        const int g    = jtg & 3;
        const int jt   = jtg >> 2;
        const int t    = lane & 31;
        const int h    = lane >> 5;
        const int j    = jt * 32 + g * 8 + h * 4;
        union { _Float16 hh[4]; uint2 u; } H, L;
        #pragma unroll
        for (int i = 0; i < 4; ++i) {
            float v = (t < T_OUT) ? Yt[(size_t)(j + i) * T_OUT + t]
                                  : (t == 8 ? 1.0f : 0.0f);
            _Float16 hi = (_Float16)v;
            H.hh[i] = hi;
            L.hh[i] = (_Float16)(v - (float)hi);
        }
        *(uint2*)(yfh + (size_t)idx * 4) = H.u;
        *(uint2*)(yfl + (size_t)idx * 4) = L.u;
        return;
    }

    // ---- feat part: rows 0..N-1 = MLP(X)*log2e; rows N.. = MLP(Y). ----
    // dim32 = X? qv : 1 ; dim33 = X? 1 : ck ; dims 34-47 = 0.
    const int rowbase = blockIdx.x * 32;
    const bool isX = rowbase < N_ROWS;
    const float* src = isX ? (X + (size_t)rowbase * D_IN)
                           : (Y + (size_t)(rowbase - N_ROWS) * D_IN);

    {
        const float4* g4 = (const float4*)src;
        int i0 = tid * 2;
        float4 v0 = g4[i0], v1 = g4[i0 + 1];
        int f0 = tid * 8;
        int r = f0 >> 6, c = f0 & 63;
        float* dst = xs + r * 65 + c;
        dst[0] = v0.x; dst[1] = v0.y; dst[2] = v0.z; dst[3] = v0.w;
        dst[4] = v1.x; dst[5] = v1.y; dst[6] = v1.z; dst[7] = v1.w;
    }
    {
        const float4* g4 = (const float4*)W1;
        int i0 = tid * 2;
        float4 v0 = g4[i0], v1 = g4[i0 + 1];
        int f0 = tid * 8;
        int r = f0 >> 5, c = f0 & 31;
        float* dst = w1l + r * 36 + c;
        ((float4*)dst)[0] = v0; ((float4*)dst)[1] = v1;
    }
    {
        int f0 = tid * 4;
        int r = f0 >> 5, c = f0 & 31;
        *(float4*)(w2l + r * 36 + c) = ((const float4*)W2)[tid];
        *(float4*)(w3l + r * 36 + c) = ((const float4*)W3)[tid];
    }
    if (tid < 32) { bl[tid] = b1[tid]; bl[32 + tid] = b2[tid]; bl[64 + tid] = b3[tid]; }
    __syncthreads();

    const int r  = tid & 31;
    const int c0 = (tid >> 5) * 4;

    float4 a1 = *(const float4*)(bl + c0);
    #pragma unroll
    for (int k = 0; k < 64; ++k) {
        float xv = xs[r * 65 + k];
        float4 w = *(const float4*)(w1l + k * 36 + c0);
        a1.x = fmaf(xv, w.x, a1.x);
        a1.y = fmaf(xv, w.y, a1.y);
        a1.z = fmaf(xv, w.z, a1.z);
        a1.w = fmaf(xv, w.w, a1.w);
    }
    h1t[(c0 + 0) * 33 + r] = fmaxf(a1.x, 0.f);
    h1t[(c0 + 1) * 33 + r] = fmaxf(a1.y, 0.f);
    h1t[(c0 + 2) * 33 + r] = fmaxf(a1.z, 0.f);
    h1t[(c0 + 3) * 33 + r] = fmaxf(a1.w, 0.f);
    __syncthreads();

    float4 a2 = *(const float4*)(bl + 32 + c0);
    #pragma unroll
    for (int k = 0; k < 32; ++k) {
        float xv = h1t[k * 33 + r];
        float4 w = *(const float4*)(w2l + k * 36 + c0);
        a2.x = fmaf(xv, w.x, a2.x);
        a2.y = fmaf(xv, w.y, a2.y);
        a2.z = fmaf(xv, w.z, a2.z);
        a2.w = fmaf(xv, w.w, a2.w);
    }
    h2t[(c0 + 0) * 33 + r] = fmaxf(a2.x, 0.f);
    h2t[(c0 + 1) * 33 + r] = fmaxf(a2.y, 0.f);
    h2t[(c0 + 2) * 33 + r] = fmaxf(a2.z, 0.f);
    h2t[(c0 + 3) * 33 + r] = fmaxf(a2.w, 0.f);
    __syncthreads();

    float4 a3 = *(const float4*)(bl + 64 + c0);
    #pragma unroll
    for (int k = 0; k < 32; ++k) {
        float xv = h2t[k * 33 + r];
        float4 w = *(const float4*)(w3l + k * 36 + c0);
        a3.x = fmaf(xv, w.x, a3.x);
        a3.y = fmaf(xv, w.y, a3.y);
        a3.z = fmaf(xv, w.z, a3.z);
        a3.w = fmaf(xv, w.w, a3.w);
    }
    float v0 = fmaxf(a3.x, 0.f), v1 = fmaxf(a3.y, 0.f);
    float v2 = fmaxf(a3.z, 0.f), v3 = fmaxf(a3.w, 0.f);

    psums[(tid >> 5) * 32 + r] = v0 * v0 + v1 * v1 + v2 * v2 + v3 * v3;

    const float scale = isX ? LOG2E : 1.0f;
    union { _Float16 h[4]; uint2 u; } hh, ll;
    float sv0 = v0 * scale, sv1 = v1 * scale, sv2 = v2 * scale, sv3 = v3 * scale;
    hh.h[0] = (_Float16)sv0; hh.h[1] = (_Float16)sv1;
    hh.h[2] = (_Float16)sv2; hh.h[3] = (_Float16)sv3;
    ll.h[0] = (_Float16)(sv0 - (float)hh.h[0]);
    ll.h[1] = (_Float16)(sv1 - (float)hh.h[1]);
    ll.h[2] = (_Float16)(sv2 - (float)hh.h[2]);
    ll.h[3] = (_Float16)(sv3 - (float)hh.h[3]);
    {
        const int tile = blockIdx.x;
        const int ch = c0 >> 4, hb = (c0 >> 3) & 1, off = c0 & 7;
        const size_t fi = (((size_t)(tile * 3 + ch) * 64) + hb * 32 + r) * 8 + off;
        *(uint2*)(fh + fi) = hh.u;
        *(uint2*)(fl + fi) = ll.u;
    }

    __syncthreads();
    if (tid < 32) {
        float nrm = 0.f;
        #pragma unroll
        for (int g = 0; g < 8; ++g) nrm += psums[g * 32 + tid];
        float qn = NHALF_SC * nrm;
        float d32 = isX ? qn : 1.0f;
        float d33 = isX ? 1.0f : qn;
        union { _Float16 h[8]; uint4 q; } eh, el, ez;
        #pragma unroll
        for (int i = 0; i < 8; ++i) { eh.h[i] = (_Float16)0.f; el.h[i] = (_Float16)0.f; ez.h[i] = (_Float16)0.f; }
        _Float16 h32 = (_Float16)d32, h33 = (_Float16)d33;
        eh.h[0] = h32; eh.h[1] = h33;
        el.h[0] = (_Float16)(d32 - (float)h32);
        el.h[1] = (_Float16)(d33 - (float)h33);
        const int tile = blockIdx.x;
        const size_t f0 = (((size_t)(tile * 3 + 2) * 64) + tid) * 8;        // dims 32-39
        const size_t f1 = (((size_t)(tile * 3 + 2) * 64) + 32 + tid) * 8;   // dims 40-47
        *(uint4*)(fh + f0) = eh.q;  *(uint4*)(fh + f1) = ez.q;
        *(uint4*)(fl + f0) = el.q;  *(uint4*)(fl + f1) = ez.q;
    }
}

// ---------------------------------------------------------------------------
// Kernel 2: fused pair kernel, block-shared LDS staging, 2-tile stages.
// R11 lesson: per-tile __syncthreads drains vmcnt(0) (structural on gfx950)
// with only ~330 cyc of compute to cover ~250-400 cyc L2 latency -> ~50%
// stall. R12: stage 2 j-tiles per buffer (40 KB LDS double-buffered),
// halving barrier count and doubling the issue->drain window to ~660 cyc.
// Math identical to R10/R11.
// ---------------------------------------------------------------------------
__global__ __launch_bounds__(256, 4) void pair_kernel(
    const _Float16* __restrict__ fh, const _Float16* __restrict__ fl,
    const _Float16* __restrict__ yfh, const _Float16* __restrict__ yfl,
    float* __restrict__ pout, float* __restrict__ psum)
{
    __shared__ char smem[2 * STAGESZ];   // 40960 B

    const int tid  = threadIdx.x;
    const int wave = tid >> 6;
    const int lane = tid & 63;
    const int n    = lane & 31;
    const int h    = lane >> 5;

    const int rowtile = blockIdx.x * 4 + wave;          // Q 32-row tile
    const int rowbase = rowtile * 32;
    const int s       = blockIdx.y;
    const int ktile0  = (N_ROWS / 32) + s * NTILES;

    // Q-side B fragments: contiguous fragment-order loads, persist in regs.
    const size_t qoff = (size_t)rowtile * 1536 + (size_t)lane * 8;
    half8 qh0 = ld_h8(fh + qoff);
    half8 qh1 = ld_h8(fh + qoff + 512);
    half8 qh2 = ld_h8(fh + qoff + 1024);
    half8 ql0 = ld_h8(fl + qoff);
    half8 ql1 = ld_h8(fl + qoff + 512);
    half8 ql2 = ld_h8(fl + qoff + 1024);

    // Stage one tile into buf: 640 16B chunks, wave-uniform regions
    // (boundaries 192/384/512/640 all multiples of 64).
    auto prefetch = [&](int jt, char* buf) {
        const char* srcKh = (const char*)(fh + (size_t)(ktile0 + jt) * 1536);
        const char* srcKl = (const char*)(fl + (size_t)(ktile0 + jt) * 1536);
        const char* srcYh = (const char*)(yfh + (size_t)(s * NTILES + jt) * 1024);
        const char* srcYl = (const char*)(yfl + (size_t)(s * NTILES + jt) * 1024);
        #pragma unroll
        for (int r = 0; r < 3; ++r) {
            const int c0 = wave * 64 + r * 256;   // wave-uniform
            const int c  = c0 + lane;
            const char* g; char* l;
            if (c0 < 192)      { g = srcKh + (size_t)c * 16;         l = buf + KH_OFF + c * 16; }
            else if (c0 < 384) { g = srcKl + (size_t)(c - 192) * 16; l = buf + KL_OFF + (c - 192) * 16; }
            else if (c0 < 512) { g = srcYh + (size_t)(c - 384) * 16; l = buf + YH_OFF + (c - 384) * 16; }
            else if (c0 < 640) { g = srcYl + (size_t)(c - 512) * 16; l = buf + YL_OFF + (c - 512) * 16; }
            else break;
            __builtin_amdgcn_global_load_lds(
                (const __attribute__((address_space(1))) void*)g,
                (__attribute__((address_space(3))) void*)l, 16, 0, 0);
        }
    };

    f32x16 o = {};   // O accumulator: col t = lane&31, row i per reg

    // Per-tile compute from an LDS tile-buffer.
    auto compute = [&](const char* cur) {
        half8 kh0 = *(const half8*)(cur + KH_OFF + lane * 16);
        half8 kh1 = *(const half8*)(cur + KH_OFF + 1024 + lane * 16);
        half8 kh2 = *(const half8*)(cur + KH_OFF + 2048 + lane * 16);
        half8 kl0 = *(const half8*)(cur + KL_OFF + lane * 16);
        half8 kl1 = *(const half8*)(cur + KL_OFF + 1024 + lane * 16);
        half8 kl2 = *(const half8*)(cur + KL_OFF + 2048 + lane * 16);

        // S^T = K·Q^T with norms folded in dims 32/33 (acc = log2e*(-sq/2))
        f32x16 acc = {};
        acc = __builtin_amdgcn_mfma_f32_32x32x16_f16(kh0, qh0, acc, 0, 0, 0);
        acc = __builtin_amdgcn_mfma_f32_32x32x16_f16(kh1, qh1, acc, 0, 0, 0);
        acc = __builtin_amdgcn_mfma_f32_32x32x16_f16(kh2, qh2, acc, 0, 0, 0);
        acc = __builtin_amdgcn_mfma_f32_32x32x16_f16(kh0, ql0, acc, 0, 0, 0);
        acc = __builtin_amdgcn_mfma_f32_32x32x16_f16(kh1, ql1, acc, 0, 0, 0);
        acc = __builtin_amdgcn_mfma_f32_32x32x16_f16(kh2, ql2, acc, 0, 0, 0);
        acc = __builtin_amdgcn_mfma_f32_32x32x16_f16(kl0, qh0, acc, 0, 0, 0);
        acc = __builtin_amdgcn_mfma_f32_32x32x16_f16(kl1, qh1, acc, 0, 0, 0);
        acc = __builtin_amdgcn_mfma_f32_32x32x16_f16(kl2, qh2, acc, 0, 0, 0);

        // Epilogue: w = 2^min(acc,0); RTZ-pack hi plane into PV A-frags.
        half4v phi[4];
        #pragma unroll
        for (int g = 0; g < 4; ++g) {
            float w0 = __builtin_amdgcn_exp2f(fminf(acc[4*g+0], 0.f));
            float w1 = __builtin_amdgcn_exp2f(fminf(acc[4*g+1], 0.f));
            float w2 = __builtin_amdgcn_exp2f(fminf(acc[4*g+2], 0.f));
            float w3 = __builtin_amdgcn_exp2f(fminf(acc[4*g+3], 0.f));
            fp16x2 p01 = __builtin_amdgcn_cvt_pkrtz(w0, w1);
            fp16x2 p23 = __builtin_amdgcn_cvt_pkrtz(w2, w3);
            union { unsigned int u[2]; half4v v; } ph;
            ph.u[0] = __builtin_bit_cast(unsigned int, p01);
            ph.u[1] = __builtin_bit_cast(unsigned int, p23);
            phi[g] = ph.v;
        }

        // PV: O += P_hi·(Ytt_hi + Ytt_lo) via 32x32x8, B-frags from LDS.
        #pragma unroll
        for (int g = 0; g < 4; ++g) {
            half4v bh = *(const half4v*)(cur + YH_OFF + (g * 64 + lane) * 8);
            half4v bv = *(const half4v*)(cur + YL_OFF + (g * 64 + lane) * 8);
            o = __builtin_amdgcn_mfma_f32_32x32x8f16(phi[g], bh, o, 0, 0, 0);
            o = __builtin_amdgcn_mfma_f32_32x32x8f16(phi[g], bv, o, 0, 0, 0);
        }
    };

    prefetch(0, smem);
    prefetch(1, smem + BUFSZ);
    __syncthreads();

    #pragma unroll
    for (int st = 0; st < NTILES / 2; ++st) {
        char* cur = smem + (st & 1) * STAGESZ;
        char* nxt = smem + ((st + 1) & 1) * STAGESZ;
        if (st + 1 < NTILES / 2) {
            prefetch(2 * st + 2, nxt);
            prefetch(2 * st + 3, nxt + BUFSZ);
        }
        compute(cur);
        compute(cur + BUFSZ);
        __syncthreads();   // drains prefetch after ~660 cyc of compute
    }

    // Writeout: col t = lane&31; rows i = (r&3)+8*(r>>2)+4h.
    const int t = n;
    if (t <= 8) {
        #pragma unroll
        for (int r = 0; r < 16; ++r) {
            int i = (r & 3) + 8 * (r >> 2) + 4 * h;
            int row = rowbase + i;
            float v = o[r];
            if (t < 8)
                pout[((size_t)s * N_ROWS + row) * T_OUT + t] = v;
            else
                psum[(size_t)s * N_ROWS + row] = v;
        }
    }
}

// ---------------------------------------------------------------------------
// Kernel 3: reduce partials across NSPLIT j-slices and normalize.
// ---------------------------------------------------------------------------
__global__ __launch_bounds__(256) void reduce_kernel(
    const float* __restrict__ pout, const float* __restrict__ psum,
    float* __restrict__ out)
{
    const int id = blockIdx.x * 256 + threadIdx.x;   // 0..65535
    const int i = id >> 3;
    float sv = 0.f, sw = 0.f;
    #pragma unroll
    for (int s = 0; s < NSPLIT; ++s) {
        sv += pout[(size_t)s * N_ROWS * T_OUT + id];
        sw += psum[(size_t)s * N_ROWS + i];
    }
    out[id] = sv / sw;
}

// ---------------------------------------------------------------------------
extern "C" void kernel_launch(void* const* d_in, const int* in_sizes, int n_in,
                              void* d_out, int out_size, void* d_ws, size_t ws_size,
                              hipStream_t stream)
{
    const float* X  = (const float*)d_in[0];
    const float* Y  = (const float*)d_in[1];
    const float* Yt = (const float*)d_in[2];
    const float* W1 = (const float*)d_in[3];
    const float* b1 = (const float*)d_in[4];
    const float* W2 = (const float*)d_in[5];
    const float* b2 = (const float*)d_in[6];
    const float* W3 = (const float*)d_in[7];
    const float* b3 = (const float*)d_in[8];
    float* out = (float*)d_out;

    char* ws = (char*)d_ws;
    const size_t n_feat = (size_t)((N_ROWS + M_ROWS) / 32) * 3 * 512;  // 786432 halves
    _Float16* fh  = (_Float16*)ws;   ws += n_feat * 2;                 // 1.5 MB
    _Float16* fl  = (_Float16*)ws;   ws += n_feat * 2;                 // 1.5 MB
    const size_t n_yf = (size_t)(M_ROWS / JTILE) * 4 * 64 * 4;         // 262144
    _Float16* yfh = (_Float16*)ws;   ws += n_yf * 2;                   // 512 KB
    _Float16* yfl = (_Float16*)ws;   ws += n_yf * 2;                   // 512 KB
    float*    pout = (float*)ws;     ws += (size_t)NSPLIT * N_ROWS * T_OUT * 4; // 8 MB
    float*    psum = (float*)ws;                                       // 1 MB

    // feat blocks (512) + ytt blocks (256) fused into one launch.
    prep_kernel<<<512 + 256, 256, 0, stream>>>(
        X, Y, Yt, W1, b1, W2, b2, W3, b3, fh, fl, yfh, yfl);

    dim3 grid2(N_ROWS / 128, NSPLIT);
    pair_kernel<<<grid2, 256, 0, stream>>>(fh, fl, yfh, yfl, pout, psum);

    reduce_kernel<<<(N_ROWS * T_OUT) / 256, 256, 0, stream>>>(pout, psum, out);
}

// Round 13
// 111.046 us; speedup vs baseline: 1.4106x; 1.0014x over previous
//
#include <hip/hip_runtime.h>
#include <hip/hip_bf16.h>
#include <cstddef>

#define N_ROWS 8192
#define M_ROWS 8192
#define D_IN   64
#define H_DIM  32
#define T_OUT  8
#define FDIM   48            // 32 features + qv/1 + 1/ck + 14 zero pad

#define NSPLIT   32          // j-splits (blockIdx.y); 2048 blocks
#define JSLICE   (M_ROWS / NSPLIT)   // 256 cols per block
#define JTILE    32
#define NTILES   (JSLICE / JTILE)    // 8 j-tiles per block
#define LOG2E    1.4426950408889634f
#define NHALF_SC (-0.72134752044448169f)   // -0.5*log2(e)

// LDS per j-tile: K hi 3072 | K lo 3072 | Y interleaved 4096 = 10240 B.
// Stage = 2 tiles = 20480 B; double-buffered = 40960 B.
#define KH_OFF 0
#define KL_OFF 3072
#define YI_OFF 6144
#define BUFSZ  10240
#define STAGESZ (2 * BUFSZ)

typedef _Float16 half8  __attribute__((ext_vector_type(8)));
typedef _Float16 half4v __attribute__((ext_vector_type(4)));
typedef __fp16   fp16x2 __attribute__((ext_vector_type(2)));
typedef float    f32x16 __attribute__((ext_vector_type(16)));

__device__ __forceinline__ half8 ld_h8(const _Float16* p) {
    return *(const half8*)p;
}

// ---------------------------------------------------------------------------
// Feature storage is FRAGMENT-ORDER: for 32-row tile T, chunk c (k-dims
// 16c..16c+15), lane l = h*32 + n holds feat[row = T*32+n][k = 16c+8h..+8)
// at ((T*3 + c)*64 + l)*8 halves — lane-contiguous 16B slices.
// Y_target PV B-fragments are stored hi|lo interleaved, 16B per (g,lane).
// ---------------------------------------------------------------------------

// ---------------------------------------------------------------------------
// Kernel 1 (fused prep): blocks 0..511 compute features (column-split MLP);
// blocks 512..767 build Y_target PV B-fragments (hi|lo interleaved).
// ---------------------------------------------------------------------------
__global__ __launch_bounds__(256) void prep_kernel(
    const float* __restrict__ X, const float* __restrict__ Y,
    const float* __restrict__ Yt,
    const float* __restrict__ W1, const float* __restrict__ b1,
    const float* __restrict__ W2, const float* __restrict__ b2,
    const float* __restrict__ W3, const float* __restrict__ b3,
    _Float16* __restrict__ fh, _Float16* __restrict__ fl,
    _Float16* __restrict__ yfi)
{
    __shared__ float xs [32 * 65];
    __shared__ float w1l[64 * 36];
    __shared__ float w2l[32 * 36];
    __shared__ float w3l[32 * 36];
    __shared__ float h1t[32 * 33];
    __shared__ float h2t[32 * 33];
    __shared__ float psums[8 * 32];
    __shared__ float bl[96];

    const int tid = threadIdx.x;

    if (blockIdx.x >= 512) {
        // ---- ytt part: Ytt[j][t] = Yt[j][t] (t<8), 1 (t==8), 0 (t>8).
        // yfi[idx*8 + 0..3] = hi, [4..7] = lo for
        // j = jt*32 + 8g + 4(l>>5) + i', t = l&31, idx = (jt*4+g)*64 + l.
        const int idx = (blockIdx.x - 512) * 256 + tid;   // 0..65535
        const int lane = idx & 63;
        const int jtg  = idx >> 6;
        const int g    = jtg & 3;
        const int jt   = jtg >> 2;
        const int t    = lane & 31;
        const int h    = lane >> 5;
        const int j    = jt * 32 + g * 8 + h * 4;
        union { _Float16 hh[8]; uint4 u; } V;
        #pragma unroll
        for (int i = 0; i < 4; ++i) {
            float v = (t < T_OUT) ? Yt[(size_t)(j + i) * T_OUT + t]
                                  : (t == 8 ? 1.0f : 0.0f);
            _Float16 hi = (_Float16)v;
            V.hh[i]     = hi;
            V.hh[4 + i] = (_Float16)(v - (float)hi);
        }
        *(uint4*)(yfi + (size_t)idx * 8) = V.u;
        return;
    }

    // ---- feat part: rows 0..N-1 = MLP(X)*log2e; rows N.. = MLP(Y). ----
    const int rowbase = blockIdx.x * 32;
    const bool isX = rowbase < N_ROWS;
    const float* src = isX ? (X + (size_t)rowbase * D_IN)
                           : (Y + (size_t)(rowbase - N_ROWS) * D_IN);

    {
        const float4* g4 = (const float4*)src;
        int i0 = tid * 2;
        float4 v0 = g4[i0], v1 = g4[i0 + 1];
        int f0 = tid * 8;
        int r = f0 >> 6, c = f0 & 63;
        float* dst = xs + r * 65 + c;
        dst[0] = v0.x; dst[1] = v0.y; dst[2] = v0.z; dst[3] = v0.w;
        dst[4] = v1.x; dst[5] = v1.y; dst[6] = v1.z; dst[7] = v1.w;
    }
    {
        const float4* g4 = (const float4*)W1;
        int i0 = tid * 2;
        float4 v0 = g4[i0], v1 = g4[i0 + 1];
        int f0 = tid * 8;
        int r = f0 >> 5, c = f0 & 31;
        float* dst = w1l + r * 36 + c;
        ((float4*)dst)[0] = v0; ((float4*)dst)[1] = v1;
    }
    {
        int f0 = tid * 4;
        int r = f0 >> 5, c = f0 & 31;
        *(float4*)(w2l + r * 36 + c) = ((const float4*)W2)[tid];
        *(float4*)(w3l + r * 36 + c) = ((const float4*)W3)[tid];
    }
    if (tid < 32) { bl[tid] = b1[tid]; bl[32 + tid] = b2[tid]; bl[64 + tid] = b3[tid]; }
    __syncthreads();

    const int r  = tid & 31;
    const int c0 = (tid >> 5) * 4;

    float4 a1 = *(const float4*)(bl + c0);
    #pragma unroll
    for (int k = 0; k < 64; ++k) {
        float xv = xs[r * 65 + k];
        float4 w = *(const float4*)(w1l + k * 36 + c0);
        a1.x = fmaf(xv, w.x, a1.x);
        a1.y = fmaf(xv, w.y, a1.y);
        a1.z = fmaf(xv, w.z, a1.z);
        a1.w = fmaf(xv, w.w, a1.w);
    }
    h1t[(c0 + 0) * 33 + r] = fmaxf(a1.x, 0.f);
    h1t[(c0 + 1) * 33 + r] = fmaxf(a1.y, 0.f);
    h1t[(c0 + 2) * 33 + r] = fmaxf(a1.z, 0.f);
    h1t[(c0 + 3) * 33 + r] = fmaxf(a1.w, 0.f);
    __syncthreads();

    float4 a2 = *(const float4*)(bl + 32 + c0);
    #pragma unroll
    for (int k = 0; k < 32; ++k) {
        float xv = h1t[k * 33 + r];
        float4 w = *(const float4*)(w2l + k * 36 + c0);
        a2.x = fmaf(xv, w.x, a2.x);
        a2.y = fmaf(xv, w.y, a2.y);
        a2.z = fmaf(xv, w.z, a2.z);
        a2.w = fmaf(xv, w.w, a2.w);
    }
    h2t[(c0 + 0) * 33 + r] = fmaxf(a2.x, 0.f);
    h2t[(c0 + 1) * 33 + r] = fmaxf(a2.y, 0.f);
    h2t[(c0 + 2) * 33 + r] = fmaxf(a2.z, 0.f);
    h2t[(c0 + 3) * 33 + r] = fmaxf(a2.w, 0.f);
    __syncthreads();

    float4 a3 = *(const float4*)(bl + 64 + c0);
    #pragma unroll
    for (int k = 0; k < 32; ++k) {
        float xv = h2t[k * 33 + r];
        float4 w = *(const float4*)(w3l + k * 36 + c0);
        a3.x = fmaf(xv, w.x, a3.x);
        a3.y = fmaf(xv, w.y, a3.y);
        a3.z = fmaf(xv, w.z, a3.z);
        a3.w = fmaf(xv, w.w, a3.w);
    }
    float v0 = fmaxf(a3.x, 0.f), v1 = fmaxf(a3.y, 0.f);
    float v2 = fmaxf(a3.z, 0.f), v3 = fmaxf(a3.w, 0.f);

    psums[(tid >> 5) * 32 + r] = v0 * v0 + v1 * v1 + v2 * v2 + v3 * v3;

    const float scale = isX ? LOG2E : 1.0f;
    union { _Float16 h[4]; uint2 u; } hh, ll;
    float sv0 = v0 * scale, sv1 = v1 * scale, sv2 = v2 * scale, sv3 = v3 * scale;
    hh.h[0] = (_Float16)sv0; hh.h[1] = (_Float16)sv1;
    hh.h[2] = (_Float16)sv2; hh.h[3] = (_Float16)sv3;
    ll.h[0] = (_Float16)(sv0 - (float)hh.h[0]);
    ll.h[1] = (_Float16)(sv1 - (float)hh.h[1]);
    ll.h[2] = (_Float16)(sv2 - (float)hh.h[2]);
    ll.h[3] = (_Float16)(sv3 - (float)hh.h[3]);
    {
        const int tile = blockIdx.x;
        const int ch = c0 >> 4, hb = (c0 >> 3) & 1, off = c0 & 7;
        const size_t fi = (((size_t)(tile * 3 + ch) * 64) + hb * 32 + r) * 8 + off;
        *(uint2*)(fh + fi) = hh.u;
        *(uint2*)(fl + fi) = ll.u;
    }

    __syncthreads();
    if (tid < 32) {
        float nrm = 0.f;
        #pragma unroll
        for (int g = 0; g < 8; ++g) nrm += psums[g * 32 + tid];
        float qn = NHALF_SC * nrm;
        float d32 = isX ? qn : 1.0f;
        float d33 = isX ? 1.0f : qn;
        union { _Float16 h[8]; uint4 q; } eh, el, ez;
        #pragma unroll
        for (int i = 0; i < 8; ++i) { eh.h[i] = (_Float16)0.f; el.h[i] = (_Float16)0.f; ez.h[i] = (_Float16)0.f; }
        _Float16 h32 = (_Float16)d32, h33 = (_Float16)d33;
        eh.h[0] = h32; eh.h[1] = h33;
        el.h[0] = (_Float16)(d32 - (float)h32);
        el.h[1] = (_Float16)(d33 - (float)h33);
        const int tile = blockIdx.x;
        const size_t f0 = (((size_t)(tile * 3 + 2) * 64) + tid) * 8;        // dims 32-39
        const size_t f1 = (((size_t)(tile * 3 + 2) * 64) + 32 + tid) * 8;   // dims 40-47
        *(uint4*)(fh + f0) = eh.q;  *(uint4*)(fh + f1) = ez.q;
        *(uint4*)(fl + f0) = el.q;  *(uint4*)(fl + f1) = ez.q;
    }
}

// ---------------------------------------------------------------------------
// Kernel 2: fused pair kernel — 2-tile INTERLEAVED compute (R13).
// Evidence ledger: time insensitive to occupancy/instr-count/addressing/L2
// traffic/barrier-rate; MfmaUtil*dur ~5x the throughput-cost of the MFMAs
// -> dependent-chain latency with too few independent chains. Fix: process
// the two staged tiles with SEPARATE accumulators (accA/accB, oA/oB),
// instructions interleaved -> 2x independent MFMA chains per wave. Y frags
// hi|lo interleaved -> b128 LDS reads. launch_bounds(256,3) for ~150-reg
// working set (R8: never starve registers; tripwire = WRITE_SIZE).
// ---------------------------------------------------------------------------
__global__ __launch_bounds__(256, 3) void pair_kernel(
    const _Float16* __restrict__ fh, const _Float16* __restrict__ fl,
    const _Float16* __restrict__ yfi,
    float* __restrict__ pout, float* __restrict__ psum)
{
    __shared__ char smem[2 * STAGESZ];   // 40960 B

    const int tid  = threadIdx.x;
    const int wave = tid >> 6;
    const int lane = tid & 63;
    const int n    = lane & 31;
    const int h    = lane >> 5;

    const int rowtile = blockIdx.x * 4 + wave;          // Q 32-row tile
    const int rowbase = rowtile * 32;
    const int s       = blockIdx.y;
    const int ktile0  = (N_ROWS / 32) + s * NTILES;

    // Q-side B fragments: contiguous fragment-order loads, persist in regs.
    const size_t qoff = (size_t)rowtile * 1536 + (size_t)lane * 8;
    half8 qh0 = ld_h8(fh + qoff);
    half8 qh1 = ld_h8(fh + qoff + 512);
    half8 qh2 = ld_h8(fh + qoff + 1024);
    half8 ql0 = ld_h8(fl + qoff);
    half8 ql1 = ld_h8(fl + qoff + 512);
    half8 ql2 = ld_h8(fl + qoff + 1024);

    // Stage one tile: KH 192 | KL 192 | YI 256 = 640 16B chunks,
    // wave-uniform regions (boundaries 192/384/640, all multiples of 64).
    auto prefetch = [&](int jt, char* buf) {
        const char* srcKh = (const char*)(fh + (size_t)(ktile0 + jt) * 1536);
        const char* srcKl = (const char*)(fl + (size_t)(ktile0 + jt) * 1536);
        const char* srcYi = (const char*)(yfi + (size_t)(s * NTILES + jt) * 2048);
        #pragma unroll
        for (int r = 0; r < 3; ++r) {
            const int c0 = wave * 64 + r * 256;   // wave-uniform
            const int c  = c0 + lane;
            const char* g; char* l;
            if (c0 < 192)      { g = srcKh + (size_t)c * 16;         l = buf + KH_OFF + c * 16; }
            else if (c0 < 384) { g = srcKl + (size_t)(c - 192) * 16; l = buf + KL_OFF + (c - 192) * 16; }
            else if (c0 < 640) { g = srcYi + (size_t)(c - 384) * 16; l = buf + YI_OFF + (c - 384) * 16; }
            else break;
            __builtin_amdgcn_global_load_lds(
                (const __attribute__((address_space(1))) void*)g,
                (__attribute__((address_space(3))) void*)l, 16, 0, 0);
        }
    };

    f32x16 oA = {}, oB = {};   // O accumulators (summed at writeout)

    // Interleaved 2-tile compute: independent QK chains and PV chains.
    auto compute2 = [&](const char* A, const char* B) {
        half8 akh0 = *(const half8*)(A + KH_OFF + lane * 16);
        half8 bkh0 = *(const half8*)(B + KH_OFF + lane * 16);
        half8 akh1 = *(const half8*)(A + KH_OFF + 1024 + lane * 16);
        half8 bkh1 = *(const half8*)(B + KH_OFF + 1024 + lane * 16);
        half8 akh2 = *(const half8*)(A + KH_OFF + 2048 + lane * 16);
        half8 bkh2 = *(const half8*)(B + KH_OFF + 2048 + lane * 16);
        half8 akl0 = *(const half8*)(A + KL_OFF + lane * 16);
        half8 bkl0 = *(const half8*)(B + KL_OFF + lane * 16);
        half8 akl1 = *(const half8*)(A + KL_OFF + 1024 + lane * 16);
        half8 bkl1 = *(const half8*)(B + KL_OFF + 1024 + lane * 16);
        half8 akl2 = *(const half8*)(A + KL_OFF + 2048 + lane * 16);
        half8 bkl2 = *(const half8*)(B + KL_OFF + 2048 + lane * 16);

        f32x16 accA = {}, accB = {};
        accA = __builtin_amdgcn_mfma_f32_32x32x16_f16(akh0, qh0, accA, 0, 0, 0);
        accB = __builtin_amdgcn_mfma_f32_32x32x16_f16(bkh0, qh0, accB, 0, 0, 0);
        accA = __builtin_amdgcn_mfma_f32_32x32x16_f16(akh1, qh1, accA, 0, 0, 0);
        accB = __builtin_amdgcn_mfma_f32_32x32x16_f16(bkh1, qh1, accB, 0, 0, 0);
        accA = __builtin_amdgcn_mfma_f32_32x32x16_f16(akh2, qh2, accA, 0, 0, 0);
        accB = __builtin_amdgcn_mfma_f32_32x32x16_f16(bkh2, qh2, accB, 0, 0, 0);
        accA = __builtin_amdgcn_mfma_f32_32x32x16_f16(akh0, ql0, accA, 0, 0, 0);
        accB = __builtin_amdgcn_mfma_f32_32x32x16_f16(bkh0, ql0, accB, 0, 0, 0);
        accA = __builtin_amdgcn_mfma_f32_32x32x16_f16(akh1, ql1, accA, 0, 0, 0);
        accB = __builtin_amdgcn_mfma_f32_32x32x16_f16(bkh1, ql1, accB, 0, 0, 0);
        accA = __builtin_amdgcn_mfma_f32_32x32x16_f16(akh2, ql2, accA, 0, 0, 0);
        accB = __builtin_amdgcn_mfma_f32_32x32x16_f16(bkh2, ql2, accB, 0, 0, 0);
        accA = __builtin_amdgcn_mfma_f32_32x32x16_f16(akl0, qh0, accA, 0, 0, 0);
        accB = __builtin_amdgcn_mfma_f32_32x32x16_f16(bkl0, qh0, accB, 0, 0, 0);
        accA = __builtin_amdgcn_mfma_f32_32x32x16_f16(akl1, qh1, accA, 0, 0, 0);
        accB = __builtin_amdgcn_mfma_f32_32x32x16_f16(bkl1, qh1, accB, 0, 0, 0);
        accA = __builtin_amdgcn_mfma_f32_32x32x16_f16(akl2, qh2, accA, 0, 0, 0);
        accB = __builtin_amdgcn_mfma_f32_32x32x16_f16(bkl2, qh2, accB, 0, 0, 0);

        // Epilogue: w = 2^min(acc,0); RTZ-pack hi plane into PV A-frags.
        half4v phiA[4], phiB[4];
        #pragma unroll
        for (int g = 0; g < 4; ++g) {
            float a0 = __builtin_amdgcn_exp2f(fminf(accA[4*g+0], 0.f));
            float a1 = __builtin_amdgcn_exp2f(fminf(accA[4*g+1], 0.f));
            float a2 = __builtin_amdgcn_exp2f(fminf(accA[4*g+2], 0.f));
            float a3 = __builtin_amdgcn_exp2f(fminf(accA[4*g+3], 0.f));
            float b0 = __builtin_amdgcn_exp2f(fminf(accB[4*g+0], 0.f));
            float b1 = __builtin_amdgcn_exp2f(fminf(accB[4*g+1], 0.f));
            float b2 = __builtin_amdgcn_exp2f(fminf(accB[4*g+2], 0.f));
            float b3 = __builtin_amdgcn_exp2f(fminf(accB[4*g+3], 0.f));
            union { unsigned int u[2]; half4v v; } pa, pb;
            pa.u[0] = __builtin_bit_cast(unsigned int, __builtin_amdgcn_cvt_pkrtz(a0, a1));
            pa.u[1] = __builtin_bit_cast(unsigned int, __builtin_amdgcn_cvt_pkrtz(a2, a3));
            pb.u[0] = __builtin_bit_cast(unsigned int, __builtin_amdgcn_cvt_pkrtz(b0, b1));
            pb.u[1] = __builtin_bit_cast(unsigned int, __builtin_amdgcn_cvt_pkrtz(b2, b3));
            phiA[g] = pa.v; phiB[g] = pb.v;
        }

        // PV: o += P_hi·(Ytt_hi + Ytt_lo) via 32x32x8, interleaved A/B.
        #pragma unroll
        for (int g = 0; g < 4; ++g) {
            uint4 ya = *(const uint4*)(A + YI_OFF + (g * 64 + lane) * 16);
            uint4 yb = *(const uint4*)(B + YI_OFF + (g * 64 + lane) * 16);
            union { unsigned int u[2]; half4v v; } ah, av, bh, bv;
            ah.u[0] = ya.x; ah.u[1] = ya.y;  av.u[0] = ya.z; av.u[1] = ya.w;
            bh.u[0] = yb.x; bh.u[1] = yb.y;  bv.u[0] = yb.z; bv.u[1] = yb.w;
            oA = __builtin_amdgcn_mfma_f32_32x32x8f16(phiA[g], ah.v, oA, 0, 0, 0);
            oB = __builtin_amdgcn_mfma_f32_32x32x8f16(phiB[g], bh.v, oB, 0, 0, 0);
            oA = __builtin_amdgcn_mfma_f32_32x32x8f16(phiA[g], av.v, oA, 0, 0, 0);
            oB = __builtin_amdgcn_mfma_f32_32x32x8f16(phiB[g], bv.v, oB, 0, 0, 0);
        }
    };

    prefetch(0, smem);
    prefetch(1, smem + BUFSZ);
    __syncthreads();

    #pragma unroll
    for (int st = 0; st < NTILES / 2; ++st) {
        char* cur = smem + (st & 1) * STAGESZ;
        char* nxt = smem + ((st + 1) & 1) * STAGESZ;
        if (st + 1 < NTILES / 2) {
            prefetch(2 * st + 2, nxt);
            prefetch(2 * st + 3, nxt + BUFSZ);
        }
        compute2(cur, cur + BUFSZ);
        __syncthreads();
    }

    // Writeout: col t = lane&31; rows i = (r&3)+8*(r>>2)+4h.
    const int t = n;
    if (t <= 8) {
        #pragma unroll
        for (int r = 0; r < 16; ++r) {
            int i = (r & 3) + 8 * (r >> 2) + 4 * h;
            int row = rowbase + i;
            float v = oA[r] + oB[r];
            if (t < 8)
                pout[((size_t)s * N_ROWS + row) * T_OUT + t] = v;
            else
                psum[(size_t)s * N_ROWS + row] = v;
        }
    }
}

// ---------------------------------------------------------------------------
// Kernel 3: reduce partials across NSPLIT j-slices and normalize.
// ---------------------------------------------------------------------------
__global__ __launch_bounds__(256) void reduce_kernel(
    const float* __restrict__ pout, const float* __restrict__ psum,
    float* __restrict__ out)
{
    const int id = blockIdx.x * 256 + threadIdx.x;   // 0..65535
    const int i = id >> 3;
    float sv = 0.f, sw = 0.f;
    #pragma unroll
    for (int s = 0; s < NSPLIT; ++s) {
        sv += pout[(size_t)s * N_ROWS * T_OUT + id];
        sw += psum[(size_t)s * N_ROWS + i];
    }
    out[id] = sv / sw;
}

// ---------------------------------------------------------------------------
extern "C" void kernel_launch(void* const* d_in, const int* in_sizes, int n_in,
                              void* d_out, int out_size, void* d_ws, size_t ws_size,
                              hipStream_t stream)
{
    const float* X  = (const float*)d_in[0];
    const float* Y  = (const float*)d_in[1];
    const float* Yt = (const float*)d_in[2];
    const float* W1 = (const float*)d_in[3];
    const float* b1 = (const float*)d_in[4];
    const float* W2 = (const float*)d_in[5];
    const float* b2 = (const float*)d_in[6];
    const float* W3 = (const float*)d_in[7];
    const float* b3 = (const float*)d_in[8];
    float* out = (float*)d_out;

    char* ws = (char*)d_ws;
    const size_t n_feat = (size_t)((N_ROWS + M_ROWS) / 32) * 3 * 512;  // 786432 halves
    _Float16* fh  = (_Float16*)ws;   ws += n_feat * 2;                 // 1.5 MB
    _Float16* fl  = (_Float16*)ws;   ws += n_feat * 2;                 // 1.5 MB
    const size_t n_yfi = (size_t)(M_ROWS / JTILE) * 4 * 64 * 8;        // 524288 halves
    _Float16* yfi = (_Float16*)ws;   ws += n_yfi * 2;                  // 1 MB
    float*    pout = (float*)ws;     ws += (size_t)NSPLIT * N_ROWS * T_OUT * 4; // 8 MB
    float*    psum = (float*)ws;                                       // 1 MB

    // feat blocks (512) + ytt blocks (256) fused into one launch.
    prep_kernel<<<512 + 256, 256, 0, stream>>>(
        X, Y, Yt, W1, b1, W2, b2, W3, b3, fh, fl, yfi);

    dim3 grid2(N_ROWS / 128, NSPLIT);
    pair_kernel<<<grid2, 256, 0, stream>>>(fh, fl, yfi, pout, psum);

    reduce_kernel<<<(N_ROWS * T_OUT) / 256, 256, 0, stream>>>(pout, psum, out);
}

// Round 15
// 103.593 us; speedup vs baseline: 1.5121x; 1.0719x over previous
//
#include <hip/hip_runtime.h>
#include <hip/hip_bf16.h>
#include <cstddef>

#define N_ROWS 8192
#define M_ROWS 8192
#define D_IN   64
#define H_DIM  32
#define T_OUT  8

#define NSPLIT   16          // j-splits (blockIdx.y); 1024 blocks = 4/CU
#define JSLICE   (M_ROWS / NSPLIT)   // 512 cols per block
#define JTILE    32
#define NTILES   (JSLICE / JTILE)    // 16 j-tiles per block
#define NSTAGES  (NTILES / 2)        // 8 two-tile stages
#define LOG2E    1.4426950408889634f
#define NHALF_SC (-0.72134752044448169f)   // -0.5*log2(e)

// Stage buffer (2 j-tiles): KH_A 2048 | KL_A 2048 | KH_B 2048 | KL_B 2048 |
// YI_A 4096 | YI_B 4096 | CK 256  = 16640 B; double-buffered = 33280 B.
#define YI_OFF  8192
#define CK_OFF  16384
#define STAGEBUF 16640

typedef _Float16 half8  __attribute__((ext_vector_type(8)));
typedef _Float16 half4v __attribute__((ext_vector_type(4)));
typedef __fp16   fp16x2 __attribute__((ext_vector_type(2)));
typedef float    f32x16 __attribute__((ext_vector_type(16)));

__device__ __forceinline__ half8 ld_h8(const _Float16* p) {
    return *(const half8*)p;
}

// ---------------------------------------------------------------------------
// Feature storage: FRAGMENT-ORDER, K=32 (2 chunks of 16; norms applied in
// the pair epilogue as exact f32). For 32-row tile T, chunk c, lane
// l = h*32+n holds feat[T*32+n][16c+8h..+8) at ((T*2 + c)*64 + l)*8 halves.
// ---------------------------------------------------------------------------

// ---------------------------------------------------------------------------
// Kernel 1 (fused prep): blocks 0..511 = features (column-split MLP) + ns;
// blocks 512..767 = Y_target PV B-fragments (hi|lo interleaved).
// ---------------------------------------------------------------------------
__global__ __launch_bounds__(256) void prep_kernel(
    const float* __restrict__ X, const float* __restrict__ Y,
    const float* __restrict__ Yt,
    const float* __restrict__ W1, const float* __restrict__ b1,
    const float* __restrict__ W2, const float* __restrict__ b2,
    const float* __restrict__ W3, const float* __restrict__ b3,
    _Float16* __restrict__ fh, _Float16* __restrict__ fl,
    _Float16* __restrict__ yfi, float* __restrict__ ns)
{
    __shared__ float xs [32 * 65];
    __shared__ float w1l[64 * 36];
    __shared__ float w2l[32 * 36];
    __shared__ float w3l[32 * 36];
    __shared__ float h1t[32 * 33];
    __shared__ float h2t[32 * 33];
    __shared__ float psums[8 * 32];
    __shared__ float bl[96];

    const int tid = threadIdx.x;

    if (blockIdx.x >= 512) {
        // Ytt[j][t] = Yt[j][t] (t<8), 1 (t==8), 0 (t>8); hi|lo interleaved.
        const int idx = (blockIdx.x - 512) * 256 + tid;   // 0..65535
        const int lane = idx & 63;
        const int jtg  = idx >> 6;
        const int g    = jtg & 3;
        const int jt   = jtg >> 2;
        const int t    = lane & 31;
        const int h    = lane >> 5;
        const int j    = jt * 32 + g * 8 + h * 4;
        union { _Float16 hh[8]; uint4 u; } V;
        #pragma unroll
        for (int i = 0; i < 4; ++i) {
            float v = (t < T_OUT) ? Yt[(size_t)(j + i) * T_OUT + t]
                                  : (t == 8 ? 1.0f : 0.0f);
            _Float16 hi = (_Float16)v;     // RNE
            V.hh[i]     = hi;
            V.hh[4 + i] = (_Float16)(v - (float)hi);
        }
        *(uint4*)(yfi + (size_t)idx * 8) = V.u;
        return;
    }

    // ---- feat: rows 0..N-1 = MLP(X)*log2e; rows N.. = MLP(Y) unscaled. ----
    const int rowbase = blockIdx.x * 32;
    const bool isX = rowbase < N_ROWS;
    const float* src = isX ? (X + (size_t)rowbase * D_IN)
                           : (Y + (size_t)(rowbase - N_ROWS) * D_IN);

    {
        const float4* g4 = (const float4*)src;
        int i0 = tid * 2;
        float4 v0 = g4[i0], v1 = g4[i0 + 1];
        int f0 = tid * 8;
        int r = f0 >> 6, c = f0 & 63;
        float* dst = xs + r * 65 + c;
        dst[0] = v0.x; dst[1] = v0.y; dst[2] = v0.z; dst[3] = v0.w;
        dst[4] = v1.x; dst[5] = v1.y; dst[6] = v1.z; dst[7] = v1.w;
    }
    {
        const float4* g4 = (const float4*)W1;
        int i0 = tid * 2;
        float4 v0 = g4[i0], v1 = g4[i0 + 1];
        int f0 = tid * 8;
        int r = f0 >> 5, c = f0 & 31;
        float* dst = w1l + r * 36 + c;
        ((float4*)dst)[0] = v0; ((float4*)dst)[1] = v1;
    }
    {
        int f0 = tid * 4;
        int r = f0 >> 5, c = f0 & 31;
        *(float4*)(w2l + r * 36 + c) = ((const float4*)W2)[tid];
        *(float4*)(w3l + r * 36 + c) = ((const float4*)W3)[tid];
    }
    if (tid < 32) { bl[tid] = b1[tid]; bl[32 + tid] = b2[tid]; bl[64 + tid] = b3[tid]; }
    __syncthreads();

    const int r  = tid & 31;
    const int c0 = (tid >> 5) * 4;

    float4 a1 = *(const float4*)(bl + c0);
    #pragma unroll
    for (int k = 0; k < 64; ++k) {
        float xv = xs[r * 65 + k];
        float4 w = *(const float4*)(w1l + k * 36 + c0);
        a1.x = fmaf(xv, w.x, a1.x);
        a1.y = fmaf(xv, w.y, a1.y);
        a1.z = fmaf(xv, w.z, a1.z);
        a1.w = fmaf(xv, w.w, a1.w);
    }
    h1t[(c0 + 0) * 33 + r] = fmaxf(a1.x, 0.f);
    h1t[(c0 + 1) * 33 + r] = fmaxf(a1.y, 0.f);
    h1t[(c0 + 2) * 33 + r] = fmaxf(a1.z, 0.f);
    h1t[(c0 + 3) * 33 + r] = fmaxf(a1.w, 0.f);
    __syncthreads();

    float4 a2 = *(const float4*)(bl + 32 + c0);
    #pragma unroll
    for (int k = 0; k < 32; ++k) {
        float xv = h1t[k * 33 + r];
        float4 w = *(const float4*)(w2l + k * 36 + c0);
        a2.x = fmaf(xv, w.x, a2.x);
        a2.y = fmaf(xv, w.y, a2.y);
        a2.z = fmaf(xv, w.z, a2.z);
        a2.w = fmaf(xv, w.w, a2.w);
    }
    h2t[(c0 + 0) * 33 + r] = fmaxf(a2.x, 0.f);
    h2t[(c0 + 1) * 33 + r] = fmaxf(a2.y, 0.f);
    h2t[(c0 + 2) * 33 + r] = fmaxf(a2.z, 0.f);
    h2t[(c0 + 3) * 33 + r] = fmaxf(a2.w, 0.f);
    __syncthreads();

    float4 a3 = *(const float4*)(bl + 64 + c0);
    #pragma unroll
    for (int k = 0; k < 32; ++k) {
        float xv = h2t[k * 33 + r];
        float4 w = *(const float4*)(w3l + k * 36 + c0);
        a3.x = fmaf(xv, w.x, a3.x);
        a3.y = fmaf(xv, w.y, a3.y);
        a3.z = fmaf(xv, w.z, a3.z);
        a3.w = fmaf(xv, w.w, a3.w);
    }
    float v0 = fmaxf(a3.x, 0.f), v1 = fmaxf(a3.y, 0.f);
    float v2 = fmaxf(a3.z, 0.f), v3 = fmaxf(a3.w, 0.f);

    psums[(tid >> 5) * 32 + r] = v0 * v0 + v1 * v1 + v2 * v2 + v3 * v3;

    const float scale = isX ? LOG2E : 1.0f;
    union { _Float16 h[4]; uint2 u; } hh, ll;
    float sv0 = v0 * scale, sv1 = v1 * scale, sv2 = v2 * scale, sv3 = v3 * scale;
    hh.h[0] = (_Float16)sv0; hh.h[1] = (_Float16)sv1;
    hh.h[2] = (_Float16)sv2; hh.h[3] = (_Float16)sv3;
    ll.h[0] = (_Float16)(sv0 - (float)hh.h[0]);
    ll.h[1] = (_Float16)(sv1 - (float)hh.h[1]);
    ll.h[2] = (_Float16)(sv2 - (float)hh.h[2]);
    ll.h[3] = (_Float16)(sv3 - (float)hh.h[3]);
    {
        const int tile = blockIdx.x;
        const int ch = c0 >> 4, hb = (c0 >> 3) & 1, off = c0 & 7;
        const size_t fi = (((size_t)(tile * 2 + ch) * 64) + hb * 32 + r) * 8 + off;
        *(uint2*)(fh + fi) = hh.u;
        *(uint2*)(fl + fi) = ll.u;
    }

    __syncthreads();
    if (tid < 32) {
        float nrm = 0.f;
        #pragma unroll
        for (int g = 0; g < 8; ++g) nrm += psums[g * 32 + tid];
        ns[rowbase + tid] = NHALF_SC * nrm;   // exact f32 norm term
    }
}

// ---------------------------------------------------------------------------
// Kernel 2: fused pair kernel (R14 structure; R15 fixes the ck staging bug:
// global_load_lds global address must be PER-LANE — the wave-uniform ptr
// replicated ck[0] across all 64 LDS slots, absmax 8.8e-2).
// Per tile: QK = 6x mfma_32x32x16 (K=32, 3-term hi/lo); norms in epilogue
// as exact f32 (qv per-lane reg, ck[64] staged per 2-tile stage). PV = 8x
// mfma_32x32x8 (hi+lo Y). MFMA cyc/tile 416->320 vs R13.
// ---------------------------------------------------------------------------
__global__ __launch_bounds__(256, 4) void pair_kernel(
    const _Float16* __restrict__ fh, const _Float16* __restrict__ fl,
    const _Float16* __restrict__ yfi, const float* __restrict__ ns,
    float* __restrict__ pout, float* __restrict__ psum)
{
    __shared__ char smem[2 * STAGEBUF];   // 33280 B

    const int tid  = threadIdx.x;
    const int wave = tid >> 6;
    const int lane = tid & 63;
    const int n    = lane & 31;
    const int h    = lane >> 5;

    const int rowtile = blockIdx.x * 4 + wave;          // Q 32-row tile
    const int rowbase = rowtile * 32;
    const int s       = blockIdx.y;
    const int ktile0  = (N_ROWS / 32) + s * NTILES;
    const int jstart  = s * JSLICE;

    // Q-side B fragments (K=32: 2 chunks, hi/lo), persist in regs.
    const size_t qoff = (size_t)rowtile * 1024 + (size_t)lane * 8;
    half8 qh0 = ld_h8(fh + qoff);
    half8 qh1 = ld_h8(fh + qoff + 512);
    half8 ql0 = ld_h8(fl + qoff);
    half8 ql1 = ld_h8(fl + qoff + 512);

    // Per-lane Q-row norm term (exact f32): row i = n.
    const float qvn = ns[rowbase + n];

    // Stage 2 tiles: 1024 16B chunks in 4 rounds + 64 ck floats (lane-indexed).
    auto prefetch = [&](int st, char* buf) {
        const int kt = ktile0 + 2 * st;
        const char* fhA = (const char*)(fh + (size_t)kt * 1024);
        const char* flA = (const char*)(fl + (size_t)kt * 1024);
        const char* fhB = (const char*)(fh + (size_t)(kt + 1) * 1024);
        const char* flB = (const char*)(fl + (size_t)(kt + 1) * 1024);
        const char* yA  = (const char*)(yfi + (size_t)(s * NTILES + 2 * st) * 2048);
        const char* yB  = (const char*)(yfi + (size_t)(s * NTILES + 2 * st + 1) * 2048);
        #pragma unroll
        for (int r = 0; r < 4; ++r) {
            const int c0 = wave * 64 + r * 256;   // wave-uniform
            const int c  = c0 + lane;
            const char* g; char* l;
            if (c0 < 128)      { g = fhA + (size_t)c * 16;         l = buf + c * 16; }
            else if (c0 < 256) { g = flA + (size_t)(c - 128) * 16; l = buf + 2048 + (c - 128) * 16; }
            else if (c0 < 384) { g = fhB + (size_t)(c - 256) * 16; l = buf + 4096 + (c - 256) * 16; }
            else if (c0 < 512) { g = flB + (size_t)(c - 384) * 16; l = buf + 6144 + (c - 384) * 16; }
            else if (c0 < 768) { g = yA  + (size_t)(c - 512) * 16; l = buf + YI_OFF + (c - 512) * 16; }
            else               { g = yB  + (size_t)(c - 768) * 16; l = buf + YI_OFF + 4096 + (c - 768) * 16; }
            __builtin_amdgcn_global_load_lds(
                (const __attribute__((address_space(1))) void*)g,
                (__attribute__((address_space(3))) void*)l, 16, 0, 0);
        }
        if (wave == 0) {
            // PER-LANE global address (R14 bug: was wave-uniform).
            const char* gc = (const char*)(ns + N_ROWS + jstart + st * 64 + lane);
            __builtin_amdgcn_global_load_lds(
                (const __attribute__((address_space(1))) void*)gc,
                (__attribute__((address_space(3))) void*)(buf + CK_OFF), 4, 0, 0);
        }
    };

    f32x16 o = {};   // O accumulator: col t = lane&31, row i per reg

    auto compute = [&](const char* buf, int sub) {
        const char* kb = buf + sub * 4096;
        half8 kh0 = *(const half8*)(kb + lane * 16);
        half8 kh1 = *(const half8*)(kb + 1024 + lane * 16);
        half8 kl0 = *(const half8*)(kb + 2048 + lane * 16);
        half8 kl1 = *(const half8*)(kb + 3072 + lane * 16);

        // S^T = K·Q^T (log2e folded into X features): 6 MFMAs, K=32.
        f32x16 acc = {};
        acc = __builtin_amdgcn_mfma_f32_32x32x16_f16(kh0, qh0, acc, 0, 0, 0);
        acc = __builtin_amdgcn_mfma_f32_32x32x16_f16(kh1, qh1, acc, 0, 0, 0);
        acc = __builtin_amdgcn_mfma_f32_32x32x16_f16(kh0, ql0, acc, 0, 0, 0);
        acc = __builtin_amdgcn_mfma_f32_32x32x16_f16(kh1, ql1, acc, 0, 0, 0);
        acc = __builtin_amdgcn_mfma_f32_32x32x16_f16(kl0, qh0, acc, 0, 0, 0);
        acc = __builtin_amdgcn_mfma_f32_32x32x16_f16(kl1, qh1, acc, 0, 0, 0);

        // Epilogue: e = acc + qv(i) + ck(j) (exact f32); w = 2^min(e,0);
        // RTZ-pack hi into PV A-frags; PV vs hi+lo Y fragments.
        // C layout: reg r in group g -> j = 8g + 4h + (r&3).
        const char* ckb = buf + CK_OFF + sub * 128;
        const char* yb  = buf + YI_OFF + sub * 4096;
        #pragma unroll
        for (int g = 0; g < 4; ++g) {
            float4 ck4 = *(const float4*)(ckb + (8 * g + 4 * h) * 4);
            float w0 = __builtin_amdgcn_exp2f(fminf(acc[4*g+0] + (ck4.x + qvn), 0.f));
            float w1 = __builtin_amdgcn_exp2f(fminf(acc[4*g+1] + (ck4.y + qvn), 0.f));
            float w2 = __builtin_amdgcn_exp2f(fminf(acc[4*g+2] + (ck4.z + qvn), 0.f));
            float w3 = __builtin_amdgcn_exp2f(fminf(acc[4*g+3] + (ck4.w + qvn), 0.f));
            union { unsigned int u[2]; half4v v; } ph;
            ph.u[0] = __builtin_bit_cast(unsigned int, __builtin_amdgcn_cvt_pkrtz(w0, w1));
            ph.u[1] = __builtin_bit_cast(unsigned int, __builtin_amdgcn_cvt_pkrtz(w2, w3));
            uint4 yv = *(const uint4*)(yb + (g * 64 + lane) * 16);
            union { unsigned int u[2]; half4v v; } yh, yl;
            yh.u[0] = yv.x; yh.u[1] = yv.y;
            yl.u[0] = yv.z; yl.u[1] = yv.w;
            o = __builtin_amdgcn_mfma_f32_32x32x8f16(ph.v, yh.v, o, 0, 0, 0);
            o = __builtin_amdgcn_mfma_f32_32x32x8f16(ph.v, yl.v, o, 0, 0, 0);
        }
    };

    prefetch(0, smem);
    __syncthreads();

    for (int st = 0; st < NSTAGES; ++st) {
        char* cur = smem + (st & 1) * STAGEBUF;
        if (st + 1 < NSTAGES) prefetch(st + 1, smem + ((st + 1) & 1) * STAGEBUF);
        compute(cur, 0);
        compute(cur, 1);
        __syncthreads();
    }

    // Writeout: col t = lane&31; rows i = (r&3)+8*(r>>2)+4h.
    const int t = n;
    if (t <= 8) {
        #pragma unroll
        for (int r = 0; r < 16; ++r) {
            int i = (r & 3) + 8 * (r >> 2) + 4 * h;
            int row = rowbase + i;
            float v = o[r];
            if (t < 8)
                pout[((size_t)s * N_ROWS + row) * T_OUT + t] = v;
            else
                psum[(size_t)s * N_ROWS + row] = v;
        }
    }
}

// ---------------------------------------------------------------------------
// Kernel 3: reduce partials across NSPLIT j-slices and normalize.
// ---------------------------------------------------------------------------
__global__ __launch_bounds__(256) void reduce_kernel(
    const float* __restrict__ pout, const float* __restrict__ psum,
    float* __restrict__ out)
{
    const int id = blockIdx.x * 256 + threadIdx.x;   // 0..65535
    const int i = id >> 3;
    float sv = 0.f, sw = 0.f;
    #pragma unroll
    for (int s = 0; s < NSPLIT; ++s) {
        sv += pout[(size_t)s * N_ROWS * T_OUT + id];
        sw += psum[(size_t)s * N_ROWS + i];
    }
    out[id] = sv / sw;
}

// ---------------------------------------------------------------------------
extern "C" void kernel_launch(void* const* d_in, const int* in_sizes, int n_in,
                              void* d_out, int out_size, void* d_ws, size_t ws_size,
                              hipStream_t stream)
{
    const float* X  = (const float*)d_in[0];
    const float* Y  = (const float*)d_in[1];
    const float* Yt = (const float*)d_in[2];
    const float* W1 = (const float*)d_in[3];
    const float* b1 = (const float*)d_in[4];
    const float* W2 = (const float*)d_in[5];
    const float* b2 = (const float*)d_in[6];
    const float* W3 = (const float*)d_in[7];
    const float* b3 = (const float*)d_in[8];
    float* out = (float*)d_out;

    char* ws = (char*)d_ws;
    const size_t n_feat = (size_t)((N_ROWS + M_ROWS) / 32) * 2 * 512;  // 524288 halves
    _Float16* fh  = (_Float16*)ws;   ws += n_feat * 2;                 // 1 MB
    _Float16* fl  = (_Float16*)ws;   ws += n_feat * 2;                 // 1 MB
    const size_t n_yfi = (size_t)(M_ROWS / JTILE) * 4 * 64 * 8;        // 524288 halves
    _Float16* yfi = (_Float16*)ws;   ws += n_yfi * 2;                  // 1 MB
    float*    ns  = (float*)ws;      ws += (N_ROWS + M_ROWS) * 4;      // 64 KB
    float*    pout = (float*)ws;     ws += (size_t)NSPLIT * N_ROWS * T_OUT * 4; // 4 MB
    float*    psum = (float*)ws;                                       // 512 KB

    // feat blocks (512) + ytt blocks (256) fused into one launch.
    prep_kernel<<<512 + 256, 256, 0, stream>>>(
        X, Y, Yt, W1, b1, W2, b2, W3, b3, fh, fl, yfi, ns);

    dim3 grid2(N_ROWS / 128, NSPLIT);
    pair_kernel<<<grid2, 256, 0, stream>>>(fh, fl, yfi, ns, pout, psum);

    reduce_kernel<<<(N_ROWS * T_OUT) / 256, 256, 0, stream>>>(pout, psum, out);
}